// Round 3
// baseline (489.245 us; speedup 1.0000x reference)
//
#include <hip/hip_runtime.h>
#include <stdint.h>

namespace {

constexpr int kB = 32, kT = 576, kC = 1024, kH = 16, kD = 64;
constexpr int kM = kB * kT;        // 18432 rows
constexpr int kNqkv = 3 * kC;      // 3072

typedef uint16_t u16;
typedef __attribute__((ext_vector_type(4))) float f32x4;
typedef __attribute__((ext_vector_type(8))) short short8;
typedef __attribute__((ext_vector_type(8))) __bf16 bf16x8;
typedef __attribute__((ext_vector_type(4))) uint16_t u16x4;

#define VMCNT(n) asm volatile("s_waitcnt vmcnt(" #n ")" ::: "memory")

__device__ __forceinline__ f32x4 mfma_bf16(short8 a, short8 b, f32x4 c) {
  return __builtin_amdgcn_mfma_f32_16x16x32_bf16(
      __builtin_bit_cast(bf16x8, a), __builtin_bit_cast(bf16x8, b), c, 0, 0, 0);
}

__device__ __forceinline__ u16 to_bf16(float x) {
  uint32_t u = __float_as_uint(x);
  u += 0x7fffu + ((u >> 16) & 1u);
  return (u16)(u >> 16);
}

__device__ __forceinline__ void gload_lds16(const void* g, void* l) {
  __builtin_amdgcn_global_load_lds(
      (const __attribute__((address_space(1))) uint32_t*)(uintptr_t)g,
      (__attribute__((address_space(3))) uint32_t*)(uintptr_t)l,
      16, 0, 0);
}

// raw barrier: no vmcnt drain. memory fences pin LDS/global ops on their side.
__device__ __forceinline__ void bar() {
  asm volatile("" ::: "memory");
  __builtin_amdgcn_s_barrier();
  asm volatile("" ::: "memory");
}

// ---- f32 -> bf16 flat cast ----
__global__ __launch_bounds__(256) void cvt_bf16_kernel(
    const float* __restrict__ in, u16* __restrict__ out, int n4) {
  const int i = blockIdx.x * 256 + threadIdx.x;
  if (i >= n4) return;
  const f32x4 v = ((const f32x4*)in)[i];
  u16x4 o;
#pragma unroll
  for (int j = 0; j < 4; ++j) o[j] = to_bf16(v[j]);
  ((u16x4*)out)[i] = o;
}

// ---- transpose-convert: in[K][N] f32 -> out[N][K] bf16 ----
__global__ void tconv_kernel(const float* __restrict__ in, u16* __restrict__ out,
                             int K, int N) {
  __shared__ u16 tile[32][33];
  const int nb = blockIdx.x * 32;
  const int kb = blockIdx.y * 32;
  const int tx = threadIdx.x;
  const int ty = threadIdx.y;
#pragma unroll
  for (int i = 0; i < 32; i += 8)
    tile[ty + i][tx] = to_bf16(in[(size_t)(kb + ty + i) * N + nb + tx]);
  __syncthreads();
#pragma unroll
  for (int i = 0; i < 32; i += 8)
    out[(size_t)(nb + ty + i) * K + kb + tx] = tile[tx][ty + i];
}

// ---- GEMM v3: 8-phase-style fine interleave, counted vmcnt, ring-4 ----
// A[M,1024] x Bt[N,1024] bf16 (+bias). BM=256, BN=NJ*64, BK=32.
// 512 thr = 8 waves (2M x 4N); per-wave out 128 x NJ*16; acc[8][NJ].
// LDS ring-4; slot = A 16KB + B (NJ*4)KB. Tiles packed [rows/2][128B]
// (first half cols 0-63, second half 64-127), swizzle colb ^= (row&7)<<4
// (0-conflict, verified r2). Staging keeps LDS dest linear and inverse-
// swizzles the per-lane GLOBAL source (rule 21).
// Per K-tile: 2 phases, each {ds_reads; stage; bar; setprio+MFMA+setprio;
// sched_barrier}; counted vmcnt only at tile boundary (steady 8/6, tail
// 4/3 -> 0 at last tile only).
// MODE 0: QKV scatter (Q*1/64, K, V^T).  MODE 1: f32 +bias.
template <int MODE, int NJ>
__global__ __launch_bounds__(512, 2) void gemm3(
    const u16* __restrict__ A, const u16* __restrict__ Bt,
    const float* __restrict__ bias, float* __restrict__ outF,
    u16* __restrict__ outQ, u16* __restrict__ outK, u16* __restrict__ outVT) {
  constexpr int Kc = 1024;
  constexpr int NT = Kc / 32;          // 32 K-tiles
  constexpr int BN = NJ * 64;          // 256 or 128
  constexpr int BHALF = BN / 2;        // packed B rows
  constexpr int SLOT = 16384 + BN * 64;
  constexpr int LB = NJ / 2;           // B loads / thread / tile
  __shared__ char lds[4][SLOT];        // 128KB (NJ=4) / 96KB (NJ=2)

  const int tid = threadIdx.x;
  const int wave = tid >> 6;
  const int lane = tid & 63;
  const int lo = lane & 15;
  const int hi = lane >> 4;
  const int wr = wave >> 2;            // 0..1: rows wr*128
  const int wc = wave & 3;             // 0..3: cols wc*(NJ*16)
  const int n0 = blockIdx.x * BN;
  const int m0 = blockIdx.y * 256;

  // inverse-swizzled staging sources
  const u16* srcA[2];
  const u16* srcB[LB];
#pragma unroll
  for (int c = 0; c < 2; ++c) {
    const int off = c * 8192 + tid * 16;
    const int row = off >> 7;
    const int col = (off & 127) ^ ((row & 7) << 4);
    const int Ar = (col < 64) ? row : row + 128;
    const int kb = (col < 64) ? col : col - 64;
    srcA[c] = A + (size_t)(m0 + Ar) * Kc + (kb >> 1);
  }
#pragma unroll
  for (int c = 0; c < LB; ++c) {
    const int off = c * 8192 + tid * 16;
    const int row = off >> 7;
    const int col = (off & 127) ^ ((row & 7) << 4);
    const int Br = (col < 64) ? row : row + BHALF;
    const int kb = (col < 64) ? col : col - 64;
    srcB[c] = Bt + (size_t)(n0 + Br) * Kc + (kb >> 1);
  }

  auto stageA = [&](int slot, int t) {
    char* base = &lds[slot][0];
#pragma unroll
    for (int c = 0; c < 2; ++c)
      gload_lds16(srcA[c] + t * 32, base + c * 8192 + wave * 1024);
  };
  auto stageB = [&](int slot, int t) {
    char* base = &lds[slot][16384];
#pragma unroll
    for (int c = 0; c < LB; ++c)
      gload_lds16(srcB[c] + t * 32, base + c * 8192 + wave * 1024);
  };

  f32x4 acc[8][NJ] = {};
  short8 af[8], bf[NJ];
  const int swz = (lo & 7) << 4;
  const int acol = wr * 64 + hi * 16;

  // prologue: tiles 0..2 staged (distance 3)
  stageA(0, 0); stageB(0, 0);
  stageA(1, 1); stageB(1, 1);
  stageA(2, 2); stageB(2, 2);
  if (NJ == 4) { VMCNT(8); } else { VMCNT(6); }   // tile 0 landed
  bar();

  for (int t = 0; t < NT; ++t) {
    const char* base = &lds[t & 3][0];
    const char* baseB = base + 16384;
    // ---- phase 0: A frags + first half of B frags, stage A(t+3)
#pragma unroll
    for (int i = 0; i < 8; ++i)
      af[i] = *(const short8*)(base + (i * 16 + lo) * 128 + (acol ^ swz));
#pragma unroll
    for (int j = 0; j < NJ / 2; ++j) {
      const int rb = wc * (NJ * 16) + j * 16 + lo;
      bf[j] = *(const short8*)(baseB + (rb & (BHALF - 1)) * 128 +
                               (((rb >= BHALF ? 64 : 0) + hi * 16) ^ swz));
    }
    if (t + 3 < NT) stageA((t + 3) & 3, t + 3);
    bar();
    __builtin_amdgcn_s_setprio(1);
#pragma unroll
    for (int j = 0; j < NJ / 2; ++j)
#pragma unroll
      for (int i = 0; i < 8; ++i)
        acc[i][j] = mfma_bf16(af[i], bf[j], acc[i][j]);
    __builtin_amdgcn_s_setprio(0);
    __builtin_amdgcn_sched_barrier(0);
    bar();
    // ---- phase 1: second half of B frags, stage B(t+3)
#pragma unroll
    for (int j = NJ / 2; j < NJ; ++j) {
      const int rb = wc * (NJ * 16) + j * 16 + lo;
      bf[j] = *(const short8*)(baseB + (rb & (BHALF - 1)) * 128 +
                               (((rb >= BHALF ? 64 : 0) + hi * 16) ^ swz));
    }
    if (t + 3 < NT) stageB((t + 3) & 3, t + 3);
    bar();
    __builtin_amdgcn_s_setprio(1);
#pragma unroll
    for (int j = NJ / 2; j < NJ; ++j)
#pragma unroll
      for (int i = 0; i < 8; ++i)
        acc[i][j] = mfma_bf16(af[i], bf[j], acc[i][j]);
    __builtin_amdgcn_s_setprio(0);
    __builtin_amdgcn_sched_barrier(0);
    // ---- tile boundary: counted wait for tile t+1 (never 0 until the last)
    if (t < NT - 1) {
      if (t + 1 <= NT - 3) { if (NJ == 4) { VMCNT(8); } else { VMCNT(6); } }
      else if (t + 1 == NT - 2) { if (NJ == 4) { VMCNT(4); } else { VMCNT(3); } }
      else { VMCNT(0); }
      bar();
    }
  }

  // epilogue. C/D frag: col = lo, row = hi*4 + r   [m89/m91]
#pragma unroll
  for (int j = 0; j < NJ; ++j) {
    const int n = n0 + wc * (NJ * 16) + j * 16 + lo;
    const float bv = bias[n];
    if (MODE == 1) {
#pragma unroll
      for (int i = 0; i < 8; ++i) {
        const int mrow = m0 + wr * 128 + i * 16 + hi * 4;
#pragma unroll
        for (int r = 0; r < 4; ++r)
          outF[(size_t)(mrow + r) * kC + n] = acc[i][j][r] + bv;
      }
    } else {
      const int which = n >> 10;
      const int c = n & 1023;
      const int hh = c >> 6;
      const int d = c & 63;
#pragma unroll
      for (int i = 0; i < 8; ++i) {
        const int mrow = m0 + wr * 128 + i * 16 + hi * 4;
#pragma unroll
        for (int r = 0; r < 4; ++r) {
          const int m = mrow + r;
          const int bb = m / kT;
          const int t = m - bb * kT;
          const float v = acc[i][j][r] + bv;
          if (which == 0)
            outQ[((size_t)(bb * kH + hh) * kT + t) * kD + d] = to_bf16(v * (1.0f / 64.0f));
          else if (which == 1)
            outK[((size_t)(bb * kH + hh) * kT + t) * kD + d] = to_bf16(v);
          else
            outVT[((size_t)(bb * kH + hh) * kD + d) * kT + t] = to_bf16(v);
        }
      }
    }
  }
}

// ---- causal flash attention (unchanged from r2).  Q pre-scaled by 1/D.
__global__ __launch_bounds__(256) void attn_kernel(
    const u16* __restrict__ Q, const u16* __restrict__ K,
    const u16* __restrict__ VT, u16* __restrict__ Y) {
  __shared__ u16 P[4][16][32];

  const int bh = blockIdx.y;
  const int qb = blockIdx.x * 64;
  const int wave = threadIdx.x >> 6;
  const int lane = threadIdx.x & 63;
  const int lo = lane & 15;
  const int hi = lane >> 4;
  const int q0 = qb + wave * 16;

  const u16* Qb = Q + (size_t)bh * kT * kD;
  const u16* Kb = K + (size_t)bh * kT * kD;
  const u16* Vb = VT + (size_t)bh * kD * kT;

  const u16* qp = Qb + (q0 + lo) * kD + hi * 8;
  const short8 qf0 = *(const short8*)qp;
  const short8 qf1 = *(const short8*)(qp + 32);

  f32x4 acc[4] = {};
  float mrun[4], lrun[4];
#pragma unroll
  for (int r = 0; r < 4; ++r) { mrun[r] = -3e38f; lrun[r] = 0.f; }

  const int kv_end = q0 + 16;
  for (int kv = 0; kv < kv_end; kv += 32) {
    f32x4 s[2];
#pragma unroll
    for (int kc = 0; kc < 2; ++kc) {
      const u16* kp = Kb + (kv + kc * 16 + lo) * kD + hi * 8;
      const short8 kf0 = *(const short8*)kp;
      const short8 kf1 = *(const short8*)(kp + 32);
      f32x4 z = {0.f, 0.f, 0.f, 0.f};
      z = mfma_bf16(qf0, kf0, z);
      z = mfma_bf16(qf1, kf1, z);
      s[kc] = z;
    }
    if (kv + 31 > q0) {
#pragma unroll
      for (int kc = 0; kc < 2; ++kc)
#pragma unroll
        for (int r = 0; r < 4; ++r)
          if (kv + kc * 16 + lo > q0 + hi * 4 + r) s[kc][r] = -3e38f;
    }
    float pm[4], rs[4], corr[4];
#pragma unroll
    for (int r = 0; r < 4; ++r) pm[r] = fmaxf(s[0][r], s[1][r]);
#pragma unroll
    for (int off = 8; off >= 1; off >>= 1)
#pragma unroll
      for (int r = 0; r < 4; ++r) pm[r] = fmaxf(pm[r], __shfl_xor(pm[r], off));
#pragma unroll
    for (int r = 0; r < 4; ++r) {
      const float mnew = fmaxf(mrun[r], pm[r]);
      corr[r] = __expf(mrun[r] - mnew);
      mrun[r] = mnew;
    }
#pragma unroll
    for (int r = 0; r < 4; ++r) {
      const float p0 = __expf(s[0][r] - mrun[r]);
      const float p1 = __expf(s[1][r] - mrun[r]);
      rs[r] = p0 + p1;
      P[wave][hi * 4 + r][lo] = to_bf16(p0);
      P[wave][hi * 4 + r][16 + lo] = to_bf16(p1);
    }
#pragma unroll
    for (int off = 8; off >= 1; off >>= 1)
#pragma unroll
      for (int r = 0; r < 4; ++r) rs[r] += __shfl_xor(rs[r], off);
#pragma unroll
    for (int r = 0; r < 4; ++r) lrun[r] = lrun[r] * corr[r] + rs[r];
#pragma unroll
    for (int nt = 0; nt < 4; ++nt)
#pragma unroll
      for (int r = 0; r < 4; ++r) acc[nt][r] *= corr[r];

    const short8 pf = *(const short8*)&P[wave][lo][hi * 8];
#pragma unroll
    for (int nt = 0; nt < 4; ++nt) {
      const short8 vf = *(const short8*)(Vb + (nt * 16 + lo) * kT + kv + hi * 8);
      acc[nt] = mfma_bf16(pf, vf, acc[nt]);
    }
  }

  const int b = bh >> 4, h = bh & 15;
#pragma unroll
  for (int r = 0; r < 4; ++r) {
    const float inv = 1.0f / lrun[r];
    const int t = q0 + hi * 4 + r;
    const size_t base = ((size_t)(b * kT + t) * kH + h) * kD;
#pragma unroll
    for (int nt = 0; nt < 4; ++nt)
      Y[base + nt * 16 + lo] = to_bf16(acc[nt][r] * inv);
  }
}

}  // namespace

extern "C" void kernel_launch(void* const* d_in, const int* in_sizes, int n_in,
                              void* d_out, int out_size, void* d_ws, size_t ws_size,
                              hipStream_t stream) {
  (void)in_sizes; (void)n_in; (void)out_size; (void)ws_size;
  const float* emb   = (const float*)d_in[0];
  const float* wqkv  = (const float*)d_in[1];
  const float* bqkv  = (const float*)d_in[2];
  const float* wproj = (const float*)d_in[3];
  const float* bproj = (const float*)d_in[4];
  float* out = (float*)d_out;

  char* p = (char*)d_ws;
  u16* embb   = (u16*)p; p += (size_t)kM * kC * 2;
  u16* wqkvt  = (u16*)p; p += (size_t)kNqkv * kC * 2;
  u16* wprojt = (u16*)p; p += (size_t)kC * kC * 2;
  u16* Qh     = (u16*)p; p += (size_t)kM * kC * 2;
  u16* Kh     = (u16*)p; p += (size_t)kM * kC * 2;
  u16* VTh    = (u16*)p; p += (size_t)kM * kC * 2;
  u16* Yh     = (u16*)p; p += (size_t)kM * kC * 2;

  const int n4 = kM * kC / 4;
  cvt_bf16_kernel<<<dim3((n4 + 255) / 256), 256, 0, stream>>>(emb, embb, n4);
  tconv_kernel<<<dim3(kNqkv / 32, kC / 32), dim3(32, 8), 0, stream>>>(wqkv, wqkvt, kC, kNqkv);
  tconv_kernel<<<dim3(kC / 32, kC / 32), dim3(32, 8), 0, stream>>>(wproj, wprojt, kC, kC);
  gemm3<0, 4><<<dim3(kNqkv / 256, kM / 256), 512, 0, stream>>>(
      embb, wqkvt, bqkv, nullptr, Qh, Kh, VTh);
  attn_kernel<<<dim3(kT / 64, kB * kH), 256, 0, stream>>>(Qh, Kh, VTh, Yh);
  gemm3<1, 2><<<dim3(kC / 128, kM / 256), 512, 0, stream>>>(
      Yh, wprojt, bproj, out, nullptr, nullptr, nullptr);
}

// Round 4
// 460.799 us; speedup vs baseline: 1.0617x; 1.0617x over previous
//
#include <hip/hip_runtime.h>
#include <stdint.h>

namespace {

constexpr int kB = 32, kT = 576, kC = 1024, kH = 16, kD = 64;
constexpr int kM = kB * kT;        // 18432 rows
constexpr int kNqkv = 3 * kC;      // 3072

typedef uint16_t u16;
typedef __attribute__((ext_vector_type(4))) float f32x4;
typedef __attribute__((ext_vector_type(8))) short short8;
typedef __attribute__((ext_vector_type(8))) __bf16 bf16x8;
typedef __attribute__((ext_vector_type(4))) uint16_t u16x4;

#define VMCNT(n) asm volatile("s_waitcnt vmcnt(" #n ")" ::: "memory")

__device__ __forceinline__ f32x4 mfma_bf16(short8 a, short8 b, f32x4 c) {
  return __builtin_amdgcn_mfma_f32_16x16x32_bf16(
      __builtin_bit_cast(bf16x8, a), __builtin_bit_cast(bf16x8, b), c, 0, 0, 0);
}

__device__ __forceinline__ u16 to_bf16(float x) {
  uint32_t u = __float_as_uint(x);
  u += 0x7fffu + ((u >> 16) & 1u);
  return (u16)(u >> 16);
}

__device__ __forceinline__ void gload_lds16(const void* g, void* l) {
  __builtin_amdgcn_global_load_lds(
      (const __attribute__((address_space(1))) uint32_t*)(uintptr_t)g,
      (__attribute__((address_space(3))) uint32_t*)(uintptr_t)l,
      16, 0, 0);
}

// raw barrier: no vmcnt drain. memory fences pin LDS/global ops on their side.
__device__ __forceinline__ void bar() {
  asm volatile("" ::: "memory");
  __builtin_amdgcn_s_barrier();
  asm volatile("" ::: "memory");
}

// ---- f32 -> bf16 flat cast ----
__global__ __launch_bounds__(256) void cvt_bf16_kernel(
    const float* __restrict__ in, u16* __restrict__ out, int n4) {
  const int i = blockIdx.x * 256 + threadIdx.x;
  if (i >= n4) return;
  const f32x4 v = ((const f32x4*)in)[i];
  u16x4 o;
#pragma unroll
  for (int j = 0; j < 4; ++j) o[j] = to_bf16(v[j]);
  ((u16x4*)out)[i] = o;
}

// ---- transpose-convert: in[K][N] f32 -> out[N][K] bf16 ----
__global__ void tconv_kernel(const float* __restrict__ in, u16* __restrict__ out,
                             int K, int N) {
  __shared__ u16 tile[32][33];
  const int nb = blockIdx.x * 32;
  const int kb = blockIdx.y * 32;
  const int tx = threadIdx.x;
  const int ty = threadIdx.y;
#pragma unroll
  for (int i = 0; i < 32; i += 8)
    tile[ty + i][tx] = to_bf16(in[(size_t)(kb + ty + i) * N + nb + tx]);
  __syncthreads();
#pragma unroll
  for (int i = 0; i < 32; i += 8)
    out[(size_t)(nb + ty + i) * K + kb + tx] = tile[tx][ty + i];
}

// ---- GEMM v4: r3 structure MINUS sched_barrier(0)  [A/B vs r3, m141 test]
// A[M,1024] x Bt[N,1024] bf16 (+bias). BM=256, BN=NJ*64, BK=32.
// 512 thr = 8 waves (2M x 4N); LDS ring-4, distance-3 prefetch;
// counted vmcnt at tile boundary only (steady 8/6, tail 4/3 -> 0 last).
// MODE 0: QKV scatter (Q*1/64, K, V^T).  MODE 1: f32 +bias.
template <int MODE, int NJ>
__global__ __launch_bounds__(512, 2) void gemm3(
    const u16* __restrict__ A, const u16* __restrict__ Bt,
    const float* __restrict__ bias, float* __restrict__ outF,
    u16* __restrict__ outQ, u16* __restrict__ outK, u16* __restrict__ outVT) {
  constexpr int Kc = 1024;
  constexpr int NT = Kc / 32;          // 32 K-tiles
  constexpr int BN = NJ * 64;          // 256 or 128
  constexpr int BHALF = BN / 2;        // packed B rows
  constexpr int SLOT = 16384 + BN * 64;
  constexpr int LB = NJ / 2;           // B loads / thread / tile
  __shared__ char lds[4][SLOT];        // 128KB (NJ=4) / 96KB (NJ=2)

  const int tid = threadIdx.x;
  const int wave = tid >> 6;
  const int lane = tid & 63;
  const int lo = lane & 15;
  const int hi = lane >> 4;
  const int wr = wave >> 2;            // 0..1: rows wr*128
  const int wc = wave & 3;             // 0..3: cols wc*(NJ*16)
  const int n0 = blockIdx.x * BN;
  const int m0 = blockIdx.y * 256;

  // inverse-swizzled staging sources (rule 21; swizzle verified 0-conflict r2)
  const u16* srcA[2];
  const u16* srcB[LB];
#pragma unroll
  for (int c = 0; c < 2; ++c) {
    const int off = c * 8192 + tid * 16;
    const int row = off >> 7;
    const int col = (off & 127) ^ ((row & 7) << 4);
    const int Ar = (col < 64) ? row : row + 128;
    const int kb = (col < 64) ? col : col - 64;
    srcA[c] = A + (size_t)(m0 + Ar) * Kc + (kb >> 1);
  }
#pragma unroll
  for (int c = 0; c < LB; ++c) {
    const int off = c * 8192 + tid * 16;
    const int row = off >> 7;
    const int col = (off & 127) ^ ((row & 7) << 4);
    const int Br = (col < 64) ? row : row + BHALF;
    const int kb = (col < 64) ? col : col - 64;
    srcB[c] = Bt + (size_t)(n0 + Br) * Kc + (kb >> 1);
  }

  auto stageA = [&](int slot, int t) {
    char* base = &lds[slot][0];
#pragma unroll
    for (int c = 0; c < 2; ++c)
      gload_lds16(srcA[c] + t * 32, base + c * 8192 + wave * 1024);
  };
  auto stageB = [&](int slot, int t) {
    char* base = &lds[slot][16384];
#pragma unroll
    for (int c = 0; c < LB; ++c)
      gload_lds16(srcB[c] + t * 32, base + c * 8192 + wave * 1024);
  };

  f32x4 acc[8][NJ] = {};
  short8 af[8], bf[NJ];
  const int swz = (lo & 7) << 4;
  const int acol = wr * 64 + hi * 16;

  // prologue: tiles 0..2 staged (distance 3)
  stageA(0, 0); stageB(0, 0);
  stageA(1, 1); stageB(1, 1);
  stageA(2, 2); stageB(2, 2);
  if (NJ == 4) { VMCNT(8); } else { VMCNT(6); }   // tile 0 landed
  bar();

  for (int t = 0; t < NT; ++t) {
    const char* base = &lds[t & 3][0];
    const char* baseB = base + 16384;
    // ---- phase 0: A frags + first half of B frags, stage A(t+3)
#pragma unroll
    for (int i = 0; i < 8; ++i)
      af[i] = *(const short8*)(base + (i * 16 + lo) * 128 + (acol ^ swz));
#pragma unroll
    for (int j = 0; j < NJ / 2; ++j) {
      const int rb = wc * (NJ * 16) + j * 16 + lo;
      bf[j] = *(const short8*)(baseB + (rb & (BHALF - 1)) * 128 +
                               (((rb >= BHALF ? 64 : 0) + hi * 16) ^ swz));
    }
    if (t + 3 < NT) stageA((t + 3) & 3, t + 3);
    bar();
    __builtin_amdgcn_s_setprio(1);
#pragma unroll
    for (int j = 0; j < NJ / 2; ++j)
#pragma unroll
      for (int i = 0; i < 8; ++i)
        acc[i][j] = mfma_bf16(af[i], bf[j], acc[i][j]);
    __builtin_amdgcn_s_setprio(0);
    bar();
    // ---- phase 1: second half of B frags, stage B(t+3)
#pragma unroll
    for (int j = NJ / 2; j < NJ; ++j) {
      const int rb = wc * (NJ * 16) + j * 16 + lo;
      bf[j] = *(const short8*)(baseB + (rb & (BHALF - 1)) * 128 +
                               (((rb >= BHALF ? 64 : 0) + hi * 16) ^ swz));
    }
    if (t + 3 < NT) stageB((t + 3) & 3, t + 3);
    bar();
    __builtin_amdgcn_s_setprio(1);
#pragma unroll
    for (int j = NJ / 2; j < NJ; ++j)
#pragma unroll
      for (int i = 0; i < 8; ++i)
        acc[i][j] = mfma_bf16(af[i], bf[j], acc[i][j]);
    __builtin_amdgcn_s_setprio(0);
    // ---- tile boundary: counted wait for tile t+1 (never 0 until the last)
    if (t < NT - 1) {
      if (t + 1 <= NT - 3) { if (NJ == 4) { VMCNT(8); } else { VMCNT(6); } }
      else if (t + 1 == NT - 2) { if (NJ == 4) { VMCNT(4); } else { VMCNT(3); } }
      else { VMCNT(0); }
      bar();
    }
  }

  // epilogue. C/D frag: col = lo, row = hi*4 + r   [m89/m91]
#pragma unroll
  for (int j = 0; j < NJ; ++j) {
    const int n = n0 + wc * (NJ * 16) + j * 16 + lo;
    const float bv = bias[n];
    if (MODE == 1) {
#pragma unroll
      for (int i = 0; i < 8; ++i) {
        const int mrow = m0 + wr * 128 + i * 16 + hi * 4;
#pragma unroll
        for (int r = 0; r < 4; ++r)
          outF[(size_t)(mrow + r) * kC + n] = acc[i][j][r] + bv;
      }
    } else {
      const int which = n >> 10;
      const int c = n & 1023;
      const int hh = c >> 6;
      const int d = c & 63;
#pragma unroll
      for (int i = 0; i < 8; ++i) {
        const int mrow = m0 + wr * 128 + i * 16 + hi * 4;
#pragma unroll
        for (int r = 0; r < 4; ++r) {
          const int m = mrow + r;
          const int bb = m / kT;
          const int t = m - bb * kT;
          const float v = acc[i][j][r] + bv;
          if (which == 0)
            outQ[((size_t)(bb * kH + hh) * kT + t) * kD + d] = to_bf16(v * (1.0f / 64.0f));
          else if (which == 1)
            outK[((size_t)(bb * kH + hh) * kT + t) * kD + d] = to_bf16(v);
          else
            outVT[((size_t)(bb * kH + hh) * kD + d) * kT + t] = to_bf16(v);
        }
      }
    }
  }
}

// ---- causal flash attention v2.  Q pre-scaled by 1/D.
// grid (ceil(T/128)=5, B*H), 4 waves/block, wave = 32 q-rows (2 frags),
// KVBLK=64. Q,K [B,H,T,D] bf16; VT [B,H,D,T] bf16; Y out [B,T,H,D] bf16.
// No barriers (wave-local LDS P tile) -> tail-wave early return is safe.
__global__ __launch_bounds__(256) void attn_kernel(
    const u16* __restrict__ Q, const u16* __restrict__ K,
    const u16* __restrict__ VT, u16* __restrict__ Y) {
  __shared__ u16 P[4][32][72];   // per-wave P tile, 144B rows (2-way banks = free)

  const int bh = blockIdx.y;
  const int wave = threadIdx.x >> 6;
  const int lane = threadIdx.x & 63;
  const int lo = lane & 15;
  const int hi = lane >> 4;
  const int q0 = blockIdx.x * 128 + wave * 32;
  if (q0 >= kT) return;          // tail block (576 = 4*128 + 64)

  const u16* Qb = Q + (size_t)bh * kT * kD;
  const u16* Kb = K + (size_t)bh * kT * kD;
  const u16* Vb = VT + (size_t)bh * kD * kT;

  short8 qf[2][2];
#pragma unroll
  for (int h = 0; h < 2; ++h) {
    const u16* qp = Qb + (q0 + h * 16 + lo) * kD + hi * 8;
    qf[h][0] = *(const short8*)qp;
    qf[h][1] = *(const short8*)(qp + 32);
  }

  f32x4 acc[2][4] = {};
  float mrun[2][4], lrun[2][4];
#pragma unroll
  for (int h = 0; h < 2; ++h)
#pragma unroll
    for (int r = 0; r < 4; ++r) { mrun[h][r] = -3e38f; lrun[h][r] = 0.f; }

  const int kv_end = q0 + 32;          // causal bound for this wave
  for (int kv = 0; kv < kv_end; kv += 64) {
    // ---- QK^T: scores s[h][kc] for 32 q-rows x 64 kv-cols
    f32x4 s[2][4];
#pragma unroll
    for (int kc = 0; kc < 4; ++kc) {
      const u16* kp = Kb + (kv + kc * 16 + lo) * kD + hi * 8;
      const short8 kf0 = *(const short8*)kp;
      const short8 kf1 = *(const short8*)(kp + 32);
#pragma unroll
      for (int h = 0; h < 2; ++h) {
        f32x4 z = {0.f, 0.f, 0.f, 0.f};
        z = mfma_bf16(qf[h][0], kf0, z);
        z = mfma_bf16(qf[h][1], kf1, z);
        s[h][kc] = z;
      }
    }
    if (kv + 63 > q0) {   // tiles crossing the diagonal: causal mask
#pragma unroll
      for (int h = 0; h < 2; ++h)
#pragma unroll
        for (int kc = 0; kc < 4; ++kc)
#pragma unroll
          for (int r = 0; r < 4; ++r)
            if (kv + kc * 16 + lo > q0 + h * 16 + hi * 4 + r) s[h][kc][r] = -3e38f;
    }
    // ---- online softmax (per 16-lane group = one q-row per (r))
#pragma unroll
    for (int h = 0; h < 2; ++h) {
      float pm[4], rs[4], corr[4];
#pragma unroll
      for (int r = 0; r < 4; ++r)
        pm[r] = fmaxf(fmaxf(s[h][0][r], s[h][1][r]), fmaxf(s[h][2][r], s[h][3][r]));
#pragma unroll
      for (int off = 8; off >= 1; off >>= 1)
#pragma unroll
        for (int r = 0; r < 4; ++r) pm[r] = fmaxf(pm[r], __shfl_xor(pm[r], off));
#pragma unroll
      for (int r = 0; r < 4; ++r) {
        const float mnew = fmaxf(mrun[h][r], pm[r]);
        corr[r] = __expf(mrun[h][r] - mnew);
        mrun[h][r] = mnew;
      }
#pragma unroll
      for (int r = 0; r < 4; ++r) {
        float acc_rs = 0.f;
#pragma unroll
        for (int kc = 0; kc < 4; ++kc) {
          const float pv = __expf(s[h][kc][r] - mrun[h][r]);
          acc_rs += pv;
          P[wave][h * 16 + hi * 4 + r][kc * 16 + lo] = to_bf16(pv);
        }
        rs[r] = acc_rs;
      }
#pragma unroll
      for (int off = 8; off >= 1; off >>= 1)
#pragma unroll
        for (int r = 0; r < 4; ++r) rs[r] += __shfl_xor(rs[r], off);
#pragma unroll
      for (int r = 0; r < 4; ++r) lrun[h][r] = lrun[h][r] * corr[r] + rs[r];
#pragma unroll
      for (int nt = 0; nt < 4; ++nt)
#pragma unroll
        for (int r = 0; r < 4; ++r) acc[h][nt][r] *= corr[r];
    }
    // ---- PV (wave-local LDS, in-order DS within a wave, no barrier)
    short8 pf[2][2];
#pragma unroll
    for (int h = 0; h < 2; ++h) {
      pf[h][0] = *(const short8*)&P[wave][h * 16 + lo][hi * 8];
      pf[h][1] = *(const short8*)&P[wave][h * 16 + lo][32 + hi * 8];
    }
#pragma unroll
    for (int nt = 0; nt < 4; ++nt) {
      const u16* vp = Vb + (nt * 16 + lo) * kT + kv + hi * 8;
      const short8 vf0 = *(const short8*)vp;
      const short8 vf1 = *(const short8*)(vp + 32);
#pragma unroll
      for (int h = 0; h < 2; ++h) {
        acc[h][nt] = mfma_bf16(pf[h][0], vf0, acc[h][nt]);
        acc[h][nt] = mfma_bf16(pf[h][1], vf1, acc[h][nt]);
      }
    }
  }

  const int b = bh >> 4, hh = bh & 15;
#pragma unroll
  for (int h = 0; h < 2; ++h)
#pragma unroll
    for (int r = 0; r < 4; ++r) {
      const float inv = 1.0f / lrun[h][r];
      const int t = q0 + h * 16 + hi * 4 + r;
      const size_t base = ((size_t)(b * kT + t) * kH + hh) * kD;
#pragma unroll
      for (int nt = 0; nt < 4; ++nt)
        Y[base + nt * 16 + lo] = to_bf16(acc[h][nt][r] * inv);
    }
}

}  // namespace

extern "C" void kernel_launch(void* const* d_in, const int* in_sizes, int n_in,
                              void* d_out, int out_size, void* d_ws, size_t ws_size,
                              hipStream_t stream) {
  (void)in_sizes; (void)n_in; (void)out_size; (void)ws_size;
  const float* emb   = (const float*)d_in[0];
  const float* wqkv  = (const float*)d_in[1];
  const float* bqkv  = (const float*)d_in[2];
  const float* wproj = (const float*)d_in[3];
  const float* bproj = (const float*)d_in[4];
  float* out = (float*)d_out;

  char* p = (char*)d_ws;
  u16* embb   = (u16*)p; p += (size_t)kM * kC * 2;
  u16* wqkvt  = (u16*)p; p += (size_t)kNqkv * kC * 2;
  u16* wprojt = (u16*)p; p += (size_t)kC * kC * 2;
  u16* Qh     = (u16*)p; p += (size_t)kM * kC * 2;
  u16* Kh     = (u16*)p; p += (size_t)kM * kC * 2;
  u16* VTh    = (u16*)p; p += (size_t)kM * kC * 2;
  u16* Yh     = (u16*)p; p += (size_t)kM * kC * 2;

  const int n4 = kM * kC / 4;
  cvt_bf16_kernel<<<dim3((n4 + 255) / 256), 256, 0, stream>>>(emb, embb, n4);
  tconv_kernel<<<dim3(kNqkv / 32, kC / 32), dim3(32, 8), 0, stream>>>(wqkv, wqkvt, kC, kNqkv);
  tconv_kernel<<<dim3(kC / 32, kC / 32), dim3(32, 8), 0, stream>>>(wproj, wprojt, kC, kC);
  gemm3<0, 4><<<dim3(kNqkv / 256, kM / 256), 512, 0, stream>>>(
      embb, wqkvt, bqkv, nullptr, Qh, Kh, VTh);
  attn_kernel<<<dim3((kT + 127) / 128, kB * kH), 256, 0, stream>>>(Qh, Kh, VTh, Yh);
  gemm3<1, 2><<<dim3(kC / 128, kM / 256), 512, 0, stream>>>(
      Yh, wprojt, bproj, out, nullptr, nullptr, nullptr);
}

// Round 5
// 371.044 us; speedup vs baseline: 1.3186x; 1.2419x over previous
//
#include <hip/hip_runtime.h>
#include <stdint.h>

namespace {

constexpr int kB = 32, kT = 576, kC = 1024, kH = 16, kD = 64;
constexpr int kM = kB * kT;        // 18432 rows
constexpr int kNqkv = 3 * kC;      // 3072

typedef uint16_t u16;
typedef __attribute__((ext_vector_type(4))) float f32x4;
typedef __attribute__((ext_vector_type(8))) short short8;
typedef __attribute__((ext_vector_type(8))) __bf16 bf16x8;
typedef __attribute__((ext_vector_type(4))) uint16_t u16x4;

#define VMCNT(n) asm volatile("s_waitcnt vmcnt(" #n ")" ::: "memory")

__device__ __forceinline__ f32x4 mfma_bf16(short8 a, short8 b, f32x4 c) {
  return __builtin_amdgcn_mfma_f32_16x16x32_bf16(
      __builtin_bit_cast(bf16x8, a), __builtin_bit_cast(bf16x8, b), c, 0, 0, 0);
}

__device__ __forceinline__ u16 to_bf16(float x) {
  uint32_t u = __float_as_uint(x);
  u += 0x7fffu + ((u >> 16) & 1u);
  return (u16)(u >> 16);
}

__device__ __forceinline__ void gload_lds16(const void* g, void* l) {
  __builtin_amdgcn_global_load_lds(
      (const __attribute__((address_space(1))) uint32_t*)(uintptr_t)g,
      (__attribute__((address_space(3))) uint32_t*)(uintptr_t)l,
      16, 0, 0);
}

// raw barrier: no vmcnt drain. memory fences pin LDS/global ops on their side.
__device__ __forceinline__ void bar() {
  asm volatile("" ::: "memory");
  __builtin_amdgcn_s_barrier();
  asm volatile("" ::: "memory");
}

// ---- f32 -> bf16 flat cast ----
__global__ __launch_bounds__(256) void cvt_bf16_kernel(
    const float* __restrict__ in, u16* __restrict__ out, int n4) {
  const int i = blockIdx.x * 256 + threadIdx.x;
  if (i >= n4) return;
  const f32x4 v = ((const f32x4*)in)[i];
  u16x4 o;
#pragma unroll
  for (int j = 0; j < 4; ++j) o[j] = to_bf16(v[j]);
  ((u16x4*)out)[i] = o;
}

// ---- transpose-convert: in[K][N] f32 -> out[N][K] bf16 ----
__global__ void tconv_kernel(const float* __restrict__ in, u16* __restrict__ out,
                             int K, int N) {
  __shared__ u16 tile[32][33];
  const int nb = blockIdx.x * 32;
  const int kb = blockIdx.y * 32;
  const int tx = threadIdx.x;
  const int ty = threadIdx.y;
#pragma unroll
  for (int i = 0; i < 32; i += 8)
    tile[ty + i][tx] = to_bf16(in[(size_t)(kb + ty + i) * N + nb + tx]);
  __syncthreads();
#pragma unroll
  for (int i = 0; i < 32; i += 8)
    out[(size_t)(nb + ty + i) * K + kb + tx] = tile[tx][ty + i];
}

// ---- QKV GEMM: r2 coarse ring-3 structure (measured 204us, 0 conflicts)
//      + XCD-chunked block remap + V^T epilogue via LDS transpose.
// A[M,1024] x Bt[3072,1024] bf16 (+bias). BM=256, BN=128, BK=64.
// 512 thr = 8 waves (2M x 4N); per-wave 128x32; acc[8][2].
// LDS ring-3 x (A 32KB + B 16KB) = 144KB; prefetch distance 2; steady
// vmcnt(12) (2 tiles x 6 loads), tail 6 -> 0.
__global__ __launch_bounds__(512, 2) void gemm_qkv(
    const u16* __restrict__ A, const u16* __restrict__ Bt,
    const float* __restrict__ bias,
    u16* __restrict__ outQ, u16* __restrict__ outK, u16* __restrict__ outVT) {
  constexpr int Kc = 1024;
  constexpr int NT = Kc / 64;          // 16 K-tiles
  __shared__ char lds[3][49152];       // slot: A @0 (32KB), B @32768 (16KB)

  const int tid = threadIdx.x;
  const int wave = tid >> 6;
  const int lane = tid & 63;
  const int lo = lane & 15;
  const int hi = lane >> 4;
  const int wr = wave >> 2;            // 0..1 -> rows wr*128
  const int wc = wave & 3;             // 0..3 -> cols wc*32

  // XCD chunking: nwg = 24*72 = 1728 = 8 * 216 (bijective)
  const int lin = blockIdx.x + blockIdx.y * 24;
  const int l2 = (lin & 7) * 216 + (lin >> 3);
  const int n0 = (l2 % 24) * 128;
  const int m0 = (l2 / 24) * 256;

  // inverse-swizzled staging sources (rows 128B; swz = (row&7)<<4; verified r2)
  const u16* srcA[4];
  const u16* srcB[2];
#pragma unroll
  for (int c = 0; c < 4; ++c) {
    const int b = c * 8192 + wave * 1024 + lane * 16;
    const int row = b >> 7;
    const int colb = (b & 127) ^ ((row & 7) << 4);
    srcA[c] = A + (size_t)(m0 + row) * Kc + (colb >> 1);
  }
#pragma unroll
  for (int c = 0; c < 2; ++c) {
    const int b = c * 8192 + wave * 1024 + lane * 16;
    const int row = b >> 7;
    const int colb = (b & 127) ^ ((row & 7) << 4);
    srcB[c] = Bt + (size_t)(n0 + row) * Kc + (colb >> 1);
  }

  auto stage = [&](int slot, int t) {       // 6 global_load_lds per thread
    const int k0 = t * 64;
    char* base = &lds[slot][0];
#pragma unroll
    for (int c = 0; c < 4; ++c)
      gload_lds16(srcA[c] + k0, base + c * 8192 + wave * 1024);
#pragma unroll
    for (int c = 0; c < 2; ++c)
      gload_lds16(srcB[c] + k0, base + 32768 + c * 8192 + wave * 1024);
  };

  f32x4 acc[8][2] = {};

  auto compute = [&](int slot) {
    const char* base = &lds[slot][0];
    __builtin_amdgcn_s_setprio(1);
#pragma unroll
    for (int ks = 0; ks < 2; ++ks) {
      const int cb = (ks * 64 + hi * 16) ^ ((lo & 7) << 4);
      short8 af[8], bfv[2];
#pragma unroll
      for (int i = 0; i < 8; ++i)
        af[i] = *(const short8*)(base + (wr * 128 + i * 16 + lo) * 128 + cb);
#pragma unroll
      for (int j = 0; j < 2; ++j)
        bfv[j] = *(const short8*)(base + 32768 + (wc * 32 + j * 16 + lo) * 128 + cb);
#pragma unroll
      for (int i = 0; i < 8; ++i)
#pragma unroll
        for (int j = 0; j < 2; ++j)
          acc[i][j] = mfma_bf16(af[i], bfv[j], acc[i][j]);
    }
    __builtin_amdgcn_s_setprio(0);
  };

  stage(0, 0);
  stage(1, 1);
  for (int t = 0; t < NT - 2; ++t) {
    stage((t + 2) % 3, t + 2);
    VMCNT(12);
    bar();
    compute(t % 3);
    bar();
  }
  VMCNT(6);
  bar();
  compute((NT - 2) % 3);
  bar();
  VMCNT(0);
  bar();
  compute((NT - 1) % 3);

  // ---- epilogue. C/D frag: col = lo, row = hi*4 + r   [m89/m91]
  if (n0 >= 2048) {
    // V block: transpose through LDS, store V^T [B,H,D,T] coalesced (8B/lane)
    bar();                                  // ring LDS now free for all waves
    u16* wlds = (u16*)&lds[0][0] + wave * (32 * 132);
    uint32_t* wlds32 = (uint32_t*)wlds;
#pragma unroll
    for (int j = 0; j < 2; ++j) {
      const int n = n0 + wc * 32 + j * 16 + lo;
      const float bv = bias[n];
#pragma unroll
      for (int i = 0; i < 8; ++i)
#pragma unroll
        for (int rp = 0; rp < 2; ++rp) {
          const u16 w0 = to_bf16(acc[i][j][rp * 2] + bv);
          const u16 w1 = to_bf16(acc[i][j][rp * 2 + 1] + bv);
          wlds32[(j * 16 + lo) * 66 + i * 8 + hi * 2 + rp] =
              (uint32_t)w0 | ((uint32_t)w1 << 16);
        }
    }
    const int l32 = lane & 31;
    const int lh = lane >> 5;
#pragma unroll
    for (int p = 0; p < 16; ++p) {
      const int d_local = p * 2 + lh;
      const int n = n0 + wc * 32 + d_local;
      const int c = n & 1023;
      const int hh = c >> 6;
      const int d = c & 63;
      const int m = m0 + wr * 128 + l32 * 4;
      const int bb = m / kT;
      const int t = m - bb * kT;
      const u16x4 v = *(const u16x4*)&wlds[d_local * 132 + l32 * 4];
      *(u16x4*)&outVT[((size_t)(bb * kH + hh) * kD + d) * kT + t] = v;
    }
  } else {
#pragma unroll
    for (int j = 0; j < 2; ++j) {
      const int n = n0 + wc * 32 + j * 16 + lo;
      const float bv = bias[n];
      const int which = n >> 10;           // 0 = Q, 1 = K (block-uniform)
      const int c = n & 1023;
      const int hh = c >> 6;
      const int d = c & 63;
#pragma unroll
      for (int i = 0; i < 8; ++i) {
        const int mrow = m0 + wr * 128 + i * 16 + hi * 4;
#pragma unroll
        for (int r = 0; r < 4; ++r) {
          const int m = mrow + r;
          const int bb = m / kT;
          const int t = m - bb * kT;
          const float v = acc[i][j][r] + bv;
          if (which == 0)
            outQ[((size_t)(bb * kH + hh) * kT + t) * kD + d] = to_bf16(v * (1.0f / 64.0f));
          else
            outK[((size_t)(bb * kH + hh) * kT + t) * kD + d] = to_bf16(v);
        }
      }
    }
  }
}

// ---- proj GEMM: 128x128, BK=32, 256 thr = 4 waves (2x2), ring-3 (48KB)
//      -> 3 blocks/CU, 12 waves/CU (latency hiding via TLP).
// LDS tile packing: [64 prow][128B]; bytes 0-63 = row prow, 64-127 = prow+64;
// swizzle byte ^= (prow&7)<<4 (same verified family). 4 loads/thread/tile;
// steady vmcnt(8), tail 4 -> 0. Epilogue f32 +bias coalesced.
__global__ __launch_bounds__(256, 3) void gemm_proj(
    const u16* __restrict__ A, const u16* __restrict__ Bt,
    const float* __restrict__ bias, float* __restrict__ outF) {
  constexpr int Kc = 1024;
  constexpr int NT = Kc / 32;           // 32 K-tiles
  __shared__ char lds[3][16384];        // slot: A @0 (8KB), B @8192 (8KB)

  const int tid = threadIdx.x;
  const int wave = tid >> 6;
  const int lane = tid & 63;
  const int lo = lane & 15;
  const int hi = lane >> 4;
  const int wr = wave >> 1;             // 0..1 -> rows wr*64
  const int wc = wave & 1;              // 0..1 -> cols wc*64

  // XCD chunking: nwg = 8*144 = 1152 = 8 * 144
  const int lin = blockIdx.x + blockIdx.y * 8;
  const int l2 = (lin & 7) * 144 + (lin >> 3);
  const int n0 = (l2 & 7) * 128;
  const int m0 = (l2 >> 3) * 128;

  const u16* srcA[2];
  const u16* srcB[2];
#pragma unroll
  for (int c = 0; c < 2; ++c) {
    const int off = c * 4096 + tid * 16;
    const int p = off >> 7;
    const int col = (off & 127) ^ ((p & 7) << 4);
    const int r_ = (col < 64) ? p : p + 64;
    const int k_ = (col & 63) >> 1;
    srcA[c] = A + (size_t)(m0 + r_) * Kc + k_;
    srcB[c] = Bt + (size_t)(n0 + r_) * Kc + k_;
  }

  auto stage = [&](int slot, int t) {       // 4 global_load_lds per thread
    char* base = &lds[slot][0];
#pragma unroll
    for (int c = 0; c < 2; ++c) {
      gload_lds16(srcA[c] + t * 32, base + c * 4096 + wave * 1024);
      gload_lds16(srcB[c] + t * 32, base + 8192 + c * 4096 + wave * 1024);
    }
  };

  f32x4 acc[4][4] = {};

  auto compute = [&](int slot) {
    const char* base = &lds[slot][0];
    const char* baseB = base + 8192;
    const int swz = (lo & 7) << 4;
    short8 af[4], bf[4];
#pragma unroll
    for (int i = 0; i < 4; ++i)
      af[i] = *(const short8*)(base + (i * 16 + lo) * 128 + ((wr * 64 + hi * 16) ^ swz));
#pragma unroll
    for (int j = 0; j < 4; ++j)
      bf[j] = *(const short8*)(baseB + (j * 16 + lo) * 128 + ((wc * 64 + hi * 16) ^ swz));
    __builtin_amdgcn_s_setprio(1);
#pragma unroll
    for (int i = 0; i < 4; ++i)
#pragma unroll
      for (int j = 0; j < 4; ++j)
        acc[i][j] = mfma_bf16(af[i], bf[j], acc[i][j]);
    __builtin_amdgcn_s_setprio(0);
  };

  stage(0, 0);
  stage(1, 1);
  for (int t = 0; t < NT - 2; ++t) {
    stage((t + 2) % 3, t + 2);
    VMCNT(8);
    bar();
    compute(t % 3);
    bar();
  }
  VMCNT(4);
  bar();
  compute((NT - 2) % 3);
  bar();
  VMCNT(0);
  bar();
  compute((NT - 1) % 3);

#pragma unroll
  for (int j = 0; j < 4; ++j) {
    const int n = n0 + wc * 64 + j * 16 + lo;
    const float bv = bias[n];
#pragma unroll
    for (int i = 0; i < 4; ++i) {
      const int mrow = m0 + wr * 64 + i * 16 + hi * 4;
#pragma unroll
      for (int r = 0; r < 4; ++r)
        outF[(size_t)(mrow + r) * kC + n] = acc[i][j][r] + bv;
    }
  }
}

// ---- causal flash attention (r4, validated).  Q pre-scaled by 1/D.
// grid (ceil(T/128)=5, B*H), 4 waves/block, wave = 32 q-rows, KVBLK=64.
__global__ __launch_bounds__(256) void attn_kernel(
    const u16* __restrict__ Q, const u16* __restrict__ K,
    const u16* __restrict__ VT, u16* __restrict__ Y) {
  __shared__ u16 P[4][32][72];   // per-wave P tile, 144B rows (2-way banks = free)

  const int bh = blockIdx.y;
  const int wave = threadIdx.x >> 6;
  const int lane = threadIdx.x & 63;
  const int lo = lane & 15;
  const int hi = lane >> 4;
  const int q0 = blockIdx.x * 128 + wave * 32;
  if (q0 >= kT) return;          // tail block (576 = 4*128 + 64)

  const u16* Qb = Q + (size_t)bh * kT * kD;
  const u16* Kb = K + (size_t)bh * kT * kD;
  const u16* Vb = VT + (size_t)bh * kD * kT;

  short8 qf[2][2];
#pragma unroll
  for (int h = 0; h < 2; ++h) {
    const u16* qp = Qb + (q0 + h * 16 + lo) * kD + hi * 8;
    qf[h][0] = *(const short8*)qp;
    qf[h][1] = *(const short8*)(qp + 32);
  }

  f32x4 acc[2][4] = {};
  float mrun[2][4], lrun[2][4];
#pragma unroll
  for (int h = 0; h < 2; ++h)
#pragma unroll
    for (int r = 0; r < 4; ++r) { mrun[h][r] = -3e38f; lrun[h][r] = 0.f; }

  const int kv_end = q0 + 32;
  for (int kv = 0; kv < kv_end; kv += 64) {
    f32x4 s[2][4];
#pragma unroll
    for (int kc = 0; kc < 4; ++kc) {
      const u16* kp = Kb + (kv + kc * 16 + lo) * kD + hi * 8;
      const short8 kf0 = *(const short8*)kp;
      const short8 kf1 = *(const short8*)(kp + 32);
#pragma unroll
      for (int h = 0; h < 2; ++h) {
        f32x4 z = {0.f, 0.f, 0.f, 0.f};
        z = mfma_bf16(qf[h][0], kf0, z);
        z = mfma_bf16(qf[h][1], kf1, z);
        s[h][kc] = z;
      }
    }
    if (kv + 63 > q0) {
#pragma unroll
      for (int h = 0; h < 2; ++h)
#pragma unroll
        for (int kc = 0; kc < 4; ++kc)
#pragma unroll
          for (int r = 0; r < 4; ++r)
            if (kv + kc * 16 + lo > q0 + h * 16 + hi * 4 + r) s[h][kc][r] = -3e38f;
    }
#pragma unroll
    for (int h = 0; h < 2; ++h) {
      float pm[4], rs[4], corr[4];
#pragma unroll
      for (int r = 0; r < 4; ++r)
        pm[r] = fmaxf(fmaxf(s[h][0][r], s[h][1][r]), fmaxf(s[h][2][r], s[h][3][r]));
#pragma unroll
      for (int off = 8; off >= 1; off >>= 1)
#pragma unroll
        for (int r = 0; r < 4; ++r) pm[r] = fmaxf(pm[r], __shfl_xor(pm[r], off));
#pragma unroll
      for (int r = 0; r < 4; ++r) {
        const float mnew = fmaxf(mrun[h][r], pm[r]);
        corr[r] = __expf(mrun[h][r] - mnew);
        mrun[h][r] = mnew;
      }
#pragma unroll
      for (int r = 0; r < 4; ++r) {
        float acc_rs = 0.f;
#pragma unroll
        for (int kc = 0; kc < 4; ++kc) {
          const float pv = __expf(s[h][kc][r] - mrun[h][r]);
          acc_rs += pv;
          P[wave][h * 16 + hi * 4 + r][kc * 16 + lo] = to_bf16(pv);
        }
        rs[r] = acc_rs;
      }
#pragma unroll
      for (int off = 8; off >= 1; off >>= 1)
#pragma unroll
        for (int r = 0; r < 4; ++r) rs[r] += __shfl_xor(rs[r], off);
#pragma unroll
      for (int r = 0; r < 4; ++r) lrun[h][r] = lrun[h][r] * corr[r] + rs[r];
#pragma unroll
      for (int nt = 0; nt < 4; ++nt)
#pragma unroll
        for (int r = 0; r < 4; ++r) acc[h][nt][r] *= corr[r];
    }
    short8 pf[2][2];
#pragma unroll
    for (int h = 0; h < 2; ++h) {
      pf[h][0] = *(const short8*)&P[wave][h * 16 + lo][hi * 8];
      pf[h][1] = *(const short8*)&P[wave][h * 16 + lo][32 + hi * 8];
    }
#pragma unroll
    for (int nt = 0; nt < 4; ++nt) {
      const u16* vp = Vb + (nt * 16 + lo) * kT + kv + hi * 8;
      const short8 vf0 = *(const short8*)vp;
      const short8 vf1 = *(const short8*)(vp + 32);
#pragma unroll
      for (int h = 0; h < 2; ++h) {
        acc[h][nt] = mfma_bf16(pf[h][0], vf0, acc[h][nt]);
        acc[h][nt] = mfma_bf16(pf[h][1], vf1, acc[h][nt]);
      }
    }
  }

  const int b = bh >> 4, hh = bh & 15;
#pragma unroll
  for (int h = 0; h < 2; ++h)
#pragma unroll
    for (int r = 0; r < 4; ++r) {
      const float inv = 1.0f / lrun[h][r];
      const int t = q0 + h * 16 + hi * 4 + r;
      const size_t base = ((size_t)(b * kT + t) * kH + hh) * kD;
#pragma unroll
      for (int nt = 0; nt < 4; ++nt)
        Y[base + nt * 16 + lo] = to_bf16(acc[h][nt][r] * inv);
    }
}

}  // namespace

extern "C" void kernel_launch(void* const* d_in, const int* in_sizes, int n_in,
                              void* d_out, int out_size, void* d_ws, size_t ws_size,
                              hipStream_t stream) {
  (void)in_sizes; (void)n_in; (void)out_size; (void)ws_size;
  const float* emb   = (const float*)d_in[0];
  const float* wqkv  = (const float*)d_in[1];
  const float* bqkv  = (const float*)d_in[2];
  const float* wproj = (const float*)d_in[3];
  const float* bproj = (const float*)d_in[4];
  float* out = (float*)d_out;

  char* p = (char*)d_ws;
  u16* embb   = (u16*)p; p += (size_t)kM * kC * 2;
  u16* wqkvt  = (u16*)p; p += (size_t)kNqkv * kC * 2;
  u16* wprojt = (u16*)p; p += (size_t)kC * kC * 2;
  u16* Qh     = (u16*)p; p += (size_t)kM * kC * 2;
  u16* Kh     = (u16*)p; p += (size_t)kM * kC * 2;
  u16* VTh    = (u16*)p; p += (size_t)kM * kC * 2;
  u16* Yh     = (u16*)p; p += (size_t)kM * kC * 2;

  const int n4 = kM * kC / 4;
  cvt_bf16_kernel<<<dim3((n4 + 255) / 256), 256, 0, stream>>>(emb, embb, n4);
  tconv_kernel<<<dim3(kNqkv / 32, kC / 32), dim3(32, 8), 0, stream>>>(wqkv, wqkvt, kC, kNqkv);
  tconv_kernel<<<dim3(kC / 32, kC / 32), dim3(32, 8), 0, stream>>>(wproj, wprojt, kC, kC);
  gemm_qkv<<<dim3(kNqkv / 128, kM / 256), 512, 0, stream>>>(
      embb, wqkvt, bqkv, Qh, Kh, VTh);
  attn_kernel<<<dim3((kT + 127) / 128, kB * kH), 256, 0, stream>>>(Qh, Kh, VTh, Yh);
  gemm_proj<<<dim3(kC / 128, kM / 128), 256, 0, stream>>>(
      Yh, wprojt, bproj, out);
}

// Round 7
// 318.981 us; speedup vs baseline: 1.5338x; 1.1632x over previous
//
#include <hip/hip_runtime.h>
#include <stdint.h>

namespace {

constexpr int kB = 32, kT = 576, kC = 1024, kH = 16, kD = 64;
constexpr int kM = kB * kT;        // 18432 rows
constexpr int kNqkv = 3 * kC;      // 3072
// Q pre-scale: 1/D for the reference's score scaling, times log2(e) so the
// attention softmax can use native v_exp_f32 (2^x) directly.
constexpr float kQScale = 1.4426950408889634f / 64.0f;

typedef uint16_t u16;
typedef __attribute__((ext_vector_type(4))) float f32x4;
typedef __attribute__((ext_vector_type(8))) short short8;
typedef __attribute__((ext_vector_type(8))) __bf16 bf16x8;
typedef __attribute__((ext_vector_type(4))) uint16_t u16x4;

#define VMCNT(n) asm volatile("s_waitcnt vmcnt(" #n ")" ::: "memory")

__device__ __forceinline__ float fexp2(float x) {
  return __builtin_amdgcn_exp2f(x);   // native v_exp_f32 (2^x)
}

__device__ __forceinline__ f32x4 mfma_bf16(short8 a, short8 b, f32x4 c) {
  return __builtin_amdgcn_mfma_f32_16x16x32_bf16(
      __builtin_bit_cast(bf16x8, a), __builtin_bit_cast(bf16x8, b), c, 0, 0, 0);
}

__device__ __forceinline__ u16 to_bf16(float x) {
  uint32_t u = __float_as_uint(x);
  u += 0x7fffu + ((u >> 16) & 1u);
  return (u16)(u >> 16);
}

__device__ __forceinline__ void gload_lds16(const void* g, void* l) {
  __builtin_amdgcn_global_load_lds(
      (const __attribute__((address_space(1))) uint32_t*)(uintptr_t)g,
      (__attribute__((address_space(3))) uint32_t*)(uintptr_t)l,
      16, 0, 0);
}

// raw barrier: no vmcnt drain. memory fences pin LDS/global ops on their side.
__device__ __forceinline__ void bar() {
  asm volatile("" ::: "memory");
  __builtin_amdgcn_s_barrier();
  asm volatile("" ::: "memory");
}

// ---- f32 -> bf16 flat cast ----
__global__ __launch_bounds__(256) void cvt_bf16_kernel(
    const float* __restrict__ in, u16* __restrict__ out, int n4) {
  const int i = blockIdx.x * 256 + threadIdx.x;
  if (i >= n4) return;
  const f32x4 v = ((const f32x4*)in)[i];
  u16x4 o;
#pragma unroll
  for (int j = 0; j < 4; ++j) o[j] = to_bf16(v[j]);
  ((u16x4*)out)[i] = o;
}

// ---- transpose-convert: in[K][N] f32 -> out[N][K] bf16 ----
__global__ void tconv_kernel(const float* __restrict__ in, u16* __restrict__ out,
                             int K, int N) {
  __shared__ u16 tile[32][33];
  const int nb = blockIdx.x * 32;
  const int kb = blockIdx.y * 32;
  const int tx = threadIdx.x;
  const int ty = threadIdx.y;
#pragma unroll
  for (int i = 0; i < 32; i += 8)
    tile[ty + i][tx] = to_bf16(in[(size_t)(kb + ty + i) * N + nb + tx]);
  __syncthreads();
#pragma unroll
  for (int i = 0; i < 32; i += 8)
    out[(size_t)(nb + ty + i) * K + kb + tx] = tile[tx][ty + i];
}

// ---- QKV GEMM (r5, validated): coarse ring-3, XCD-chunked, V^T via LDS ----
__global__ __launch_bounds__(512, 2) void gemm_qkv(
    const u16* __restrict__ A, const u16* __restrict__ Bt,
    const float* __restrict__ bias,
    u16* __restrict__ outQ, u16* __restrict__ outK, u16* __restrict__ outVT) {
  constexpr int Kc = 1024;
  constexpr int NT = Kc / 64;          // 16 K-tiles
  __shared__ char lds[3][49152];       // slot: A @0 (32KB), B @32768 (16KB)

  const int tid = threadIdx.x;
  const int wave = tid >> 6;
  const int lane = tid & 63;
  const int lo = lane & 15;
  const int hi = lane >> 4;
  const int wr = wave >> 2;
  const int wc = wave & 3;

  // XCD chunking: nwg = 24*72 = 1728 = 8 * 216 (bijective)
  const int lin = blockIdx.x + blockIdx.y * 24;
  const int l2 = (lin & 7) * 216 + (lin >> 3);
  const int n0 = (l2 % 24) * 128;
  const int m0 = (l2 / 24) * 256;

  const u16* srcA[4];
  const u16* srcB[2];
#pragma unroll
  for (int c = 0; c < 4; ++c) {
    const int b = c * 8192 + wave * 1024 + lane * 16;
    const int row = b >> 7;
    const int colb = (b & 127) ^ ((row & 7) << 4);
    srcA[c] = A + (size_t)(m0 + row) * Kc + (colb >> 1);
  }
#pragma unroll
  for (int c = 0; c < 2; ++c) {
    const int b = c * 8192 + wave * 1024 + lane * 16;
    const int row = b >> 7;
    const int colb = (b & 127) ^ ((row & 7) << 4);
    srcB[c] = Bt + (size_t)(n0 + row) * Kc + (colb >> 1);
  }

  auto stage = [&](int slot, int t) {
    const int k0 = t * 64;
    char* base = &lds[slot][0];
#pragma unroll
    for (int c = 0; c < 4; ++c)
      gload_lds16(srcA[c] + k0, base + c * 8192 + wave * 1024);
#pragma unroll
    for (int c = 0; c < 2; ++c)
      gload_lds16(srcB[c] + k0, base + 32768 + c * 8192 + wave * 1024);
  };

  f32x4 acc[8][2] = {};

  auto compute = [&](int slot) {
    const char* base = &lds[slot][0];
    __builtin_amdgcn_s_setprio(1);
#pragma unroll
    for (int ks = 0; ks < 2; ++ks) {
      const int cb = (ks * 64 + hi * 16) ^ ((lo & 7) << 4);
      short8 af[8], bfv[2];
#pragma unroll
      for (int i = 0; i < 8; ++i)
        af[i] = *(const short8*)(base + (wr * 128 + i * 16 + lo) * 128 + cb);
#pragma unroll
      for (int j = 0; j < 2; ++j)
        bfv[j] = *(const short8*)(base + 32768 + (wc * 32 + j * 16 + lo) * 128 + cb);
#pragma unroll
      for (int i = 0; i < 8; ++i)
#pragma unroll
        for (int j = 0; j < 2; ++j)
          acc[i][j] = mfma_bf16(af[i], bfv[j], acc[i][j]);
    }
    __builtin_amdgcn_s_setprio(0);
  };

  stage(0, 0);
  stage(1, 1);
  for (int t = 0; t < NT - 2; ++t) {
    stage((t + 2) % 3, t + 2);
    VMCNT(12);
    bar();
    compute(t % 3);
    bar();
  }
  VMCNT(6);
  bar();
  compute((NT - 2) % 3);
  bar();
  VMCNT(0);
  bar();
  compute((NT - 1) % 3);

  // ---- epilogue. C/D frag: col = lo, row = hi*4 + r   [m89/m91]
  if (n0 >= 2048) {
    // V block: transpose through LDS, store V^T [B,H,D,T] coalesced
    bar();
    u16* wlds = (u16*)&lds[0][0] + wave * (32 * 132);
    uint32_t* wlds32 = (uint32_t*)wlds;
#pragma unroll
    for (int j = 0; j < 2; ++j) {
      const int n = n0 + wc * 32 + j * 16 + lo;
      const float bv = bias[n];
#pragma unroll
      for (int i = 0; i < 8; ++i)
#pragma unroll
        for (int rp = 0; rp < 2; ++rp) {
          const u16 w0 = to_bf16(acc[i][j][rp * 2] + bv);
          const u16 w1 = to_bf16(acc[i][j][rp * 2 + 1] + bv);
          wlds32[(j * 16 + lo) * 66 + i * 8 + hi * 2 + rp] =
              (uint32_t)w0 | ((uint32_t)w1 << 16);
        }
    }
    const int l32 = lane & 31;
    const int lh = lane >> 5;
#pragma unroll
    for (int p = 0; p < 16; ++p) {
      const int d_local = p * 2 + lh;
      const int n = n0 + wc * 32 + d_local;
      const int c = n & 1023;
      const int hh = c >> 6;
      const int d = c & 63;
      const int m = m0 + wr * 128 + l32 * 4;
      const int bb = m / kT;
      const int t = m - bb * kT;
      const u16x4 v = *(const u16x4*)&wlds[d_local * 132 + l32 * 4];
      *(u16x4*)&outVT[((size_t)(bb * kH + hh) * kD + d) * kT + t] = v;
    }
  } else {
#pragma unroll
    for (int j = 0; j < 2; ++j) {
      const int n = n0 + wc * 32 + j * 16 + lo;
      const float bv = bias[n];
      const int which = n >> 10;
      const int c = n & 1023;
      const int hh = c >> 6;
      const int d = c & 63;
#pragma unroll
      for (int i = 0; i < 8; ++i) {
        const int mrow = m0 + wr * 128 + i * 16 + hi * 4;
#pragma unroll
        for (int r = 0; r < 4; ++r) {
          const int m = mrow + r;
          const int bb = m / kT;
          const int t = m - bb * kT;
          const float v = acc[i][j][r] + bv;
          if (which == 0)       // Q pre-scaled for exp2-softmax
            outQ[((size_t)(bb * kH + hh) * kT + t) * kD + d] = to_bf16(v * kQScale);
          else
            outK[((size_t)(bb * kH + hh) * kT + t) * kD + d] = to_bf16(v);
        }
      }
    }
  }
}

// ---- proj GEMM (r5, validated): 128x128, BK=32, ring-3, 3 blocks/CU ----
__global__ __launch_bounds__(256, 3) void gemm_proj(
    const u16* __restrict__ A, const u16* __restrict__ Bt,
    const float* __restrict__ bias, float* __restrict__ outF) {
  constexpr int Kc = 1024;
  constexpr int NT = Kc / 32;
  __shared__ char lds[3][16384];

  const int tid = threadIdx.x;
  const int wave = tid >> 6;
  const int lane = tid & 63;
  const int lo = lane & 15;
  const int hi = lane >> 4;
  const int wr = wave >> 1;
  const int wc = wave & 1;

  const int lin = blockIdx.x + blockIdx.y * 8;
  const int l2 = (lin & 7) * 144 + (lin >> 3);
  const int n0 = (l2 & 7) * 128;
  const int m0 = (l2 >> 3) * 128;

  const u16* srcA[2];
  const u16* srcB[2];
#pragma unroll
  for (int c = 0; c < 2; ++c) {
    const int off = c * 4096 + tid * 16;
    const int p = off >> 7;
    const int col = (off & 127) ^ ((p & 7) << 4);
    const int r_ = (col < 64) ? p : p + 64;
    const int k_ = (col & 63) >> 1;
    srcA[c] = A + (size_t)(m0 + r_) * Kc + k_;
    srcB[c] = Bt + (size_t)(n0 + r_) * Kc + k_;
  }

  auto stage = [&](int slot, int t) {
    char* base = &lds[slot][0];
#pragma unroll
    for (int c = 0; c < 2; ++c) {
      gload_lds16(srcA[c] + t * 32, base + c * 4096 + wave * 1024);
      gload_lds16(srcB[c] + t * 32, base + 8192 + c * 4096 + wave * 1024);
    }
  };

  f32x4 acc[4][4] = {};

  auto compute = [&](int slot) {
    const char* base = &lds[slot][0];
    const char* baseB = base + 8192;
    const int swz = (lo & 7) << 4;
    short8 af[4], bf[4];
#pragma unroll
    for (int i = 0; i < 4; ++i)
      af[i] = *(const short8*)(base + (i * 16 + lo) * 128 + ((wr * 64 + hi * 16) ^ swz));
#pragma unroll
    for (int j = 0; j < 4; ++j)
      bf[j] = *(const short8*)(baseB + (j * 16 + lo) * 128 + ((wc * 64 + hi * 16) ^ swz));
    __builtin_amdgcn_s_setprio(1);
#pragma unroll
    for (int i = 0; i < 4; ++i)
#pragma unroll
      for (int j = 0; j < 4; ++j)
        acc[i][j] = mfma_bf16(af[i], bf[j], acc[i][j]);
    __builtin_amdgcn_s_setprio(0);
  };

  stage(0, 0);
  stage(1, 1);
  for (int t = 0; t < NT - 2; ++t) {
    stage((t + 2) % 3, t + 2);
    VMCNT(8);
    bar();
    compute(t % 3);
    bar();
  }
  VMCNT(4);
  bar();
  compute((NT - 2) % 3);
  bar();
  VMCNT(0);
  bar();
  compute((NT - 1) % 3);

#pragma unroll
  for (int j = 0; j < 4; ++j) {
    const int n = n0 + wc * 64 + j * 16 + lo;
    const float bv = bias[n];
#pragma unroll
    for (int i = 0; i < 4; ++i) {
      const int mrow = m0 + wr * 64 + i * 16 + hi * 4;
#pragma unroll
      for (int r = 0; r < 4; ++r)
        outF[(size_t)(mrow + r) * kC + n] = acc[i][j][r] + bv;
    }
  }
}

// ---- causal flash attention v3: swapped QK^T, deferred denom, exp2,
//      reg-prefetch of K(next)/V(cur), heavy-first 1-D grid.
// Q pre-scaled by log2(e)/64.  Q,K [B,H,T,D]; VT [B,H,D,T]; Y [B,T,H,D].
// 1-D grid of 2560 = 5 q-tiles x 512 bh, heaviest q-tiles dispatched first.
// Each wave: 32 q-rows (2 h-frags), KVBLK=64, no barriers (wave-local P).
// Swapped layout: s[h][kc][r] = S[q=q0+h*16+lo][k=kv+kc*16+hi*4+r]
//   -> row-max = in-reg tree + shfl_xor(16,32); sum deferred to end.
__global__ __launch_bounds__(256) void attn_kernel(
    const u16* __restrict__ Q, const u16* __restrict__ K,
    const u16* __restrict__ VT, u16* __restrict__ Y) {
  __shared__ u16 P[4][32][72];   // per-wave P tile, 144B rows

  const int idx = blockIdx.x;
  const int qi = 4 - (idx >> 9);     // heavy-first
  const int bh = idx & 511;
  const int wave = threadIdx.x >> 6;
  const int lane = threadIdx.x & 63;
  const int lo = lane & 15;
  const int hi = lane >> 4;
  const int q0 = qi * 128 + wave * 32;
  if (q0 >= kT) return;

  const u16* Qb = Q + (size_t)bh * kT * kD;
  const u16* Kb = K + (size_t)bh * kT * kD;
  const u16* Vb = VT + (size_t)bh * kD * kT;

  short8 qf[2][2];
#pragma unroll
  for (int h = 0; h < 2; ++h) {
    const u16* qp = Qb + (q0 + h * 16 + lo) * kD + hi * 8;
    qf[h][0] = *(const short8*)qp;
    qf[h][1] = *(const short8*)(qp + 32);
  }

  f32x4 acc[2][4] = {};
  float mrun[2] = {-3e38f, -3e38f};
  float lsum[2] = {0.f, 0.f};

  // preload K tile for kv=0
  short8 kf[4][2];
#pragma unroll
  for (int kc = 0; kc < 4; ++kc) {
    const u16* kp = Kb + (kc * 16 + lo) * kD + hi * 8;
    kf[kc][0] = *(const short8*)kp;
    kf[kc][1] = *(const short8*)(kp + 32);
  }

  const int kv_end = q0 + 32;
  for (int kv = 0; kv < kv_end; kv += 64) {
    // ---- QK^T (swapped operands): lane owns q-row q0+h*16+lo
    f32x4 s[2][4];
#pragma unroll
    for (int kc = 0; kc < 4; ++kc)
#pragma unroll
      for (int h = 0; h < 2; ++h) {
        f32x4 z = {0.f, 0.f, 0.f, 0.f};
        z = mfma_bf16(kf[kc][0], qf[h][0], z);
        z = mfma_bf16(kf[kc][1], qf[h][1], z);
        s[h][kc] = z;
      }
    // ---- kf regs now dead: issue V(cur) and K(next) loads; they fly
    //      during the softmax VALU phase below.
    short8 vf[4][2];
#pragma unroll
    for (int nt = 0; nt < 4; ++nt) {
      const u16* vp = Vb + (nt * 16 + lo) * kT + kv + hi * 8;
      vf[nt][0] = *(const short8*)vp;
      vf[nt][1] = *(const short8*)(vp + 32);
    }
    if (kv + 64 < kv_end) {
#pragma unroll
      for (int kc = 0; kc < 4; ++kc) {
        const u16* kp = Kb + (kv + 64 + kc * 16 + lo) * kD + hi * 8;
        kf[kc][0] = *(const short8*)kp;
        kf[kc][1] = *(const short8*)(kp + 32);
      }
    }
    // ---- causal mask (k = kv+kc*16+hi*4+r, q = q0+h*16+lo)
    if (kv + 63 > q0) {
#pragma unroll
      for (int h = 0; h < 2; ++h) {
        const int q = q0 + h * 16 + lo;
#pragma unroll
        for (int kc = 0; kc < 4; ++kc)
#pragma unroll
          for (int r = 0; r < 4; ++r)
            if (kv + kc * 16 + hi * 4 + r > q) s[h][kc][r] = -3e38f;
      }
    }
    // ---- online softmax, lane-local row
#pragma unroll
    for (int h = 0; h < 2; ++h) {
      float m01 = fmaxf(fmaxf(s[h][0][0], s[h][0][1]), fmaxf(s[h][0][2], s[h][0][3]));
      float m23 = fmaxf(fmaxf(s[h][1][0], s[h][1][1]), fmaxf(s[h][1][2], s[h][1][3]));
      float m45 = fmaxf(fmaxf(s[h][2][0], s[h][2][1]), fmaxf(s[h][2][2], s[h][2][3]));
      float m67 = fmaxf(fmaxf(s[h][3][0], s[h][3][1]), fmaxf(s[h][3][2], s[h][3][3]));
      float pm = fmaxf(fmaxf(m01, m23), fmaxf(m45, m67));
      pm = fmaxf(pm, __shfl_xor(pm, 16));
      pm = fmaxf(pm, __shfl_xor(pm, 32));
      const float mnew = fmaxf(mrun[h], pm);
      const float corr = fexp2(mrun[h] - mnew);
      mrun[h] = mnew;
      float psum = 0.f;
#pragma unroll
      for (int kc = 0; kc < 4; ++kc) {
        u16x4 pk;
#pragma unroll
        for (int r = 0; r < 4; ++r) {
          const float pv = fexp2(s[h][kc][r] - mnew);
          psum += pv;
          pk[r] = to_bf16(pv);
        }
        *(u16x4*)&P[wave][h * 16 + lo][kc * 16 + hi * 4] = pk;
      }
      lsum[h] = lsum[h] * corr + psum;     // per-lane partial (16 k-slots)
#pragma unroll
      for (int nt = 0; nt < 4; ++nt)
#pragma unroll
        for (int r = 0; r < 4; ++r) acc[h][nt][r] *= corr;
    }
    // ---- PV (wave-local LDS round-trip for P transpose)
    short8 pf[2][2];
#pragma unroll
    for (int h = 0; h < 2; ++h) {
      pf[h][0] = *(const short8*)&P[wave][h * 16 + lo][hi * 8];
      pf[h][1] = *(const short8*)&P[wave][h * 16 + lo][32 + hi * 8];
    }
#pragma unroll
    for (int nt = 0; nt < 4; ++nt)
#pragma unroll
      for (int h = 0; h < 2; ++h) {
        acc[h][nt] = mfma_bf16(pf[h][0], vf[nt][0], acc[h][nt]);
        acc[h][nt] = mfma_bf16(pf[h][1], vf[nt][1], acc[h][nt]);
      }
  }

  // ---- final denominator: reduce lane partials over the 4 hi-groups,
  //      then redistribute to the acc row-index space (row = hi*4+r lives
  //      at source lane lo' = hi*4+r after the reduce).
#pragma unroll
  for (int h = 0; h < 2; ++h) {
    lsum[h] += __shfl_xor(lsum[h], 16);
    lsum[h] += __shfl_xor(lsum[h], 32);
  }
  const int b = bh >> 4, hh = bh & 15;
#pragma unroll
  for (int h = 0; h < 2; ++h)
#pragma unroll
    for (int r = 0; r < 4; ++r) {
      const float linv = 1.0f / __shfl(lsum[h], hi * 4 + r);
      const int t = q0 + h * 16 + hi * 4 + r;
      const size_t base = ((size_t)(b * kT + t) * kH + hh) * kD;
#pragma unroll
      for (int nt = 0; nt < 4; ++nt)
        Y[base + nt * 16 + lo] = to_bf16(acc[h][nt][r] * linv);
    }
}

}  // namespace

extern "C" void kernel_launch(void* const* d_in, const int* in_sizes, int n_in,
                              void* d_out, int out_size, void* d_ws, size_t ws_size,
                              hipStream_t stream) {
  (void)in_sizes; (void)n_in; (void)out_size; (void)ws_size;
  const float* emb   = (const float*)d_in[0];
  const float* wqkv  = (const float*)d_in[1];
  const float* bqkv  = (const float*)d_in[2];
  const float* wproj = (const float*)d_in[3];
  const float* bproj = (const float*)d_in[4];
  float* out = (float*)d_out;

  char* p = (char*)d_ws;
  u16* embb   = (u16*)p; p += (size_t)kM * kC * 2;
  u16* wqkvt  = (u16*)p; p += (size_t)kNqkv * kC * 2;
  u16* wprojt = (u16*)p; p += (size_t)kC * kC * 2;
  u16* Qh     = (u16*)p; p += (size_t)kM * kC * 2;
  u16* Kh     = (u16*)p; p += (size_t)kM * kC * 2;
  u16* VTh    = (u16*)p; p += (size_t)kM * kC * 2;
  u16* Yh     = (u16*)p; p += (size_t)kM * kC * 2;

  const int n4 = kM * kC / 4;
  cvt_bf16_kernel<<<dim3((n4 + 255) / 256), 256, 0, stream>>>(emb, embb, n4);
  tconv_kernel<<<dim3(kNqkv / 32, kC / 32), dim3(32, 8), 0, stream>>>(wqkv, wqkvt, kC, kNqkv);
  tconv_kernel<<<dim3(kC / 32, kC / 32), dim3(32, 8), 0, stream>>>(wproj, wprojt, kC, kC);
  gemm_qkv<<<dim3(kNqkv / 128, kM / 256), 512, 0, stream>>>(
      embb, wqkvt, bqkv, Qh, Kh, VTh);
  attn_kernel<<<dim3(5 * kB * kH), 256, 0, stream>>>(Qh, Kh, VTh, Yh);
  gemm_proj<<<dim3(kC / 128, kM / 128), 256, 0, stream>>>(
      Yh, wprojt, bproj, out);
}

// Round 8
// 317.383 us; speedup vs baseline: 1.5415x; 1.0050x over previous
//
#include <hip/hip_runtime.h>
#include <stdint.h>

namespace {

constexpr int kB = 32, kT = 576, kC = 1024, kH = 16, kD = 64;
constexpr int kM = kB * kT;        // 18432 rows
constexpr int kNqkv = 3 * kC;      // 3072
// Q pre-scale: 1/D for the reference's score scaling, times log2(e) so the
// attention softmax can use native v_exp_f32 (2^x) directly.
constexpr float kQScale = 1.4426950408889634f / 64.0f;

typedef uint16_t u16;
typedef __attribute__((ext_vector_type(4))) float f32x4;
typedef __attribute__((ext_vector_type(8))) short short8;
typedef __attribute__((ext_vector_type(8))) __bf16 bf16x8;
typedef __attribute__((ext_vector_type(4))) uint16_t u16x4;

#define VMCNT(n) asm volatile("s_waitcnt vmcnt(" #n ")" ::: "memory")

__device__ __forceinline__ float fexp2(float x) {
  return __builtin_amdgcn_exp2f(x);   // native v_exp_f32 (2^x)
}

__device__ __forceinline__ f32x4 mfma_bf16(short8 a, short8 b, f32x4 c) {
  return __builtin_amdgcn_mfma_f32_16x16x32_bf16(
      __builtin_bit_cast(bf16x8, a), __builtin_bit_cast(bf16x8, b), c, 0, 0, 0);
}

__device__ __forceinline__ u16 to_bf16(float x) {
  uint32_t u = __float_as_uint(x);
  u += 0x7fffu + ((u >> 16) & 1u);
  return (u16)(u >> 16);
}

__device__ __forceinline__ void gload_lds16(const void* g, void* l) {
  __builtin_amdgcn_global_load_lds(
      (const __attribute__((address_space(1))) uint32_t*)(uintptr_t)g,
      (__attribute__((address_space(3))) uint32_t*)(uintptr_t)l,
      16, 0, 0);
}

// raw barrier: no vmcnt drain. memory fences pin LDS/global ops on their side.
__device__ __forceinline__ void bar() {
  asm volatile("" ::: "memory");
  __builtin_amdgcn_s_barrier();
  asm volatile("" ::: "memory");
}

// ---- f32 -> bf16 flat cast ----
__global__ __launch_bounds__(256) void cvt_bf16_kernel(
    const float* __restrict__ in, u16* __restrict__ out, int n4) {
  const int i = blockIdx.x * 256 + threadIdx.x;
  if (i >= n4) return;
  const f32x4 v = ((const f32x4*)in)[i];
  u16x4 o;
#pragma unroll
  for (int j = 0; j < 4; ++j) o[j] = to_bf16(v[j]);
  ((u16x4*)out)[i] = o;
}

// ---- transpose-convert: in[K][N] f32 -> out[N][K] bf16 ----
__global__ void tconv_kernel(const float* __restrict__ in, u16* __restrict__ out,
                             int K, int N) {
  __shared__ u16 tile[32][33];
  const int nb = blockIdx.x * 32;
  const int kb = blockIdx.y * 32;
  const int tx = threadIdx.x;
  const int ty = threadIdx.y;
#pragma unroll
  for (int i = 0; i < 32; i += 8)
    tile[ty + i][tx] = to_bf16(in[(size_t)(kb + ty + i) * N + nb + tx]);
  __syncthreads();
#pragma unroll
  for (int i = 0; i < 32; i += 8)
    out[(size_t)(nb + ty + i) * K + kb + tx] = tile[tx][ty + i];
}

// ---- QKV GEMM v3: coarse ring-3 (r5) with SQUARE per-wave tiles.
// Wave split 4M x 2N -> per-wave 64x64 output, acc[4][4].
// LDS fragment traffic per K-tile: 8 waves x 16KB = 128KB (was 160KB with
// 128x32 waves) -> LDS-BW bound resource cut 20%.  All staging, swizzle,
// vmcnt schedule, XCD chunking identical to r5/r7 (validated).
__global__ __launch_bounds__(512, 2) void gemm_qkv(
    const u16* __restrict__ A, const u16* __restrict__ Bt,
    const float* __restrict__ bias,
    u16* __restrict__ outQ, u16* __restrict__ outK, u16* __restrict__ outVT) {
  constexpr int Kc = 1024;
  constexpr int NT = Kc / 64;          // 16 K-tiles
  __shared__ char lds[3][49152];       // slot: A @0 (32KB), B @32768 (16KB)

  const int tid = threadIdx.x;
  const int wave = tid >> 6;
  const int lane = tid & 63;
  const int lo = lane & 15;
  const int hi = lane >> 4;
  const int wr = wave >> 1;            // 0..3 -> rows wr*64
  const int wc = wave & 1;             // 0..1 -> cols wc*64

  // XCD chunking: nwg = 24*72 = 1728 = 8 * 216 (bijective)
  const int lin = blockIdx.x + blockIdx.y * 24;
  const int l2 = (lin & 7) * 216 + (lin >> 3);
  const int n0 = (l2 % 24) * 128;
  const int m0 = (l2 / 24) * 256;

  const u16* srcA[4];
  const u16* srcB[2];
#pragma unroll
  for (int c = 0; c < 4; ++c) {
    const int b = c * 8192 + wave * 1024 + lane * 16;
    const int row = b >> 7;
    const int colb = (b & 127) ^ ((row & 7) << 4);
    srcA[c] = A + (size_t)(m0 + row) * Kc + (colb >> 1);
  }
#pragma unroll
  for (int c = 0; c < 2; ++c) {
    const int b = c * 8192 + wave * 1024 + lane * 16;
    const int row = b >> 7;
    const int colb = (b & 127) ^ ((row & 7) << 4);
    srcB[c] = Bt + (size_t)(n0 + row) * Kc + (colb >> 1);
  }

  auto stage = [&](int slot, int t) {
    const int k0 = t * 64;
    char* base = &lds[slot][0];
#pragma unroll
    for (int c = 0; c < 4; ++c)
      gload_lds16(srcA[c] + k0, base + c * 8192 + wave * 1024);
#pragma unroll
    for (int c = 0; c < 2; ++c)
      gload_lds16(srcB[c] + k0, base + 32768 + c * 8192 + wave * 1024);
  };

  f32x4 acc[4][4] = {};

  auto compute = [&](int slot) {
    const char* base = &lds[slot][0];
    __builtin_amdgcn_s_setprio(1);
#pragma unroll
    for (int ks = 0; ks < 2; ++ks) {
      const int cb = (ks * 64 + hi * 16) ^ ((lo & 7) << 4);
      short8 af[4], bfv[4];
#pragma unroll
      for (int i = 0; i < 4; ++i)
        af[i] = *(const short8*)(base + (wr * 64 + i * 16 + lo) * 128 + cb);
#pragma unroll
      for (int j = 0; j < 4; ++j)
        bfv[j] = *(const short8*)(base + 32768 + (wc * 64 + j * 16 + lo) * 128 + cb);
#pragma unroll
      for (int i = 0; i < 4; ++i)
#pragma unroll
        for (int j = 0; j < 4; ++j)
          acc[i][j] = mfma_bf16(af[i], bfv[j], acc[i][j]);
    }
    __builtin_amdgcn_s_setprio(0);
  };

  stage(0, 0);
  stage(1, 1);
  for (int t = 0; t < NT - 2; ++t) {
    stage((t + 2) % 3, t + 2);
    VMCNT(12);
    bar();
    compute(t % 3);
    bar();
  }
  VMCNT(6);
  bar();
  compute((NT - 2) % 3);
  bar();
  VMCNT(0);
  bar();
  compute((NT - 1) % 3);

  // ---- epilogue. C/D frag: col = lo, row = hi*4 + r   [m89/m91]
  if (n0 >= 2048) {
    // V block: transpose through LDS (per-wave [64 d][66] u16 tile),
    // store V^T [B,H,D,T] coalesced (8B/lane, 64 consecutive t per group).
    bar();                                  // ring LDS now free for all waves
    u16* wlds = (u16*)&lds[0][0] + wave * (64 * 66);
    uint32_t* wlds32 = (uint32_t*)wlds;
#pragma unroll
    for (int j = 0; j < 4; ++j) {
      const int n = n0 + wc * 64 + j * 16 + lo;
      const float bv = bias[n];
#pragma unroll
      for (int i = 0; i < 4; ++i)
#pragma unroll
        for (int rp = 0; rp < 2; ++rp) {
          const u16 w0 = to_bf16(acc[i][j][rp * 2] + bv);
          const u16 w1 = to_bf16(acc[i][j][rp * 2 + 1] + bv);
          // d_local = j*16+lo (row, stride 33 u32), m_local = i*16+hi*4+rp*2
          wlds32[(j * 16 + lo) * 33 + i * 8 + hi * 2 + rp] =
              (uint32_t)w0 | ((uint32_t)w1 << 16);
        }
    }
#pragma unroll
    for (int p = 0; p < 16; ++p) {
      const int d_local = p * 4 + hi;        // 64 d rows
      const int n = n0 + wc * 64 + d_local;
      const int c = n & 1023;
      const int hh = c >> 6;
      const int d = c & 63;
      const int m = m0 + wr * 64 + lo * 4;   // 64 m per group of 16 lanes
      const int bb = m / kT;
      const int t = m - bb * kT;
      const u16x4 v = *(const u16x4*)&wlds[d_local * 66 + lo * 4];
      *(u16x4*)&outVT[((size_t)(bb * kH + hh) * kD + d) * kT + t] = v;
    }
  } else {
#pragma unroll
    for (int j = 0; j < 4; ++j) {
      const int n = n0 + wc * 64 + j * 16 + lo;
      const float bv = bias[n];
      const int which = n >> 10;             // block-uniform (128 | 1024)
      const int c = n & 1023;
      const int hh = c >> 6;
      const int d = c & 63;
#pragma unroll
      for (int i = 0; i < 4; ++i) {
        const int mrow = m0 + wr * 64 + i * 16 + hi * 4;
#pragma unroll
        for (int r = 0; r < 4; ++r) {
          const int m = mrow + r;
          const int bb = m / kT;
          const int t = m - bb * kT;
          const float v = acc[i][j][r] + bv;
          if (which == 0)       // Q pre-scaled for exp2-softmax
            outQ[((size_t)(bb * kH + hh) * kT + t) * kD + d] = to_bf16(v * kQScale);
          else
            outK[((size_t)(bb * kH + hh) * kT + t) * kD + d] = to_bf16(v);
        }
      }
    }
  }
}

// ---- proj GEMM (r5, validated): 128x128, BK=32, ring-3, 3 blocks/CU ----
__global__ __launch_bounds__(256, 3) void gemm_proj(
    const u16* __restrict__ A, const u16* __restrict__ Bt,
    const float* __restrict__ bias, float* __restrict__ outF) {
  constexpr int Kc = 1024;
  constexpr int NT = Kc / 32;
  __shared__ char lds[3][16384];

  const int tid = threadIdx.x;
  const int wave = tid >> 6;
  const int lane = tid & 63;
  const int lo = lane & 15;
  const int hi = lane >> 4;
  const int wr = wave >> 1;
  const int wc = wave & 1;

  const int lin = blockIdx.x + blockIdx.y * 8;
  const int l2 = (lin & 7) * 144 + (lin >> 3);
  const int n0 = (l2 & 7) * 128;
  const int m0 = (l2 >> 3) * 128;

  const u16* srcA[2];
  const u16* srcB[2];
#pragma unroll
  for (int c = 0; c < 2; ++c) {
    const int off = c * 4096 + tid * 16;
    const int p = off >> 7;
    const int col = (off & 127) ^ ((p & 7) << 4);
    const int r_ = (col < 64) ? p : p + 64;
    const int k_ = (col & 63) >> 1;
    srcA[c] = A + (size_t)(m0 + r_) * Kc + k_;
    srcB[c] = Bt + (size_t)(n0 + r_) * Kc + k_;
  }

  auto stage = [&](int slot, int t) {
    char* base = &lds[slot][0];
#pragma unroll
    for (int c = 0; c < 2; ++c) {
      gload_lds16(srcA[c] + t * 32, base + c * 4096 + wave * 1024);
      gload_lds16(srcB[c] + t * 32, base + 8192 + c * 4096 + wave * 1024);
    }
  };

  f32x4 acc[4][4] = {};

  auto compute = [&](int slot) {
    const char* base = &lds[slot][0];
    const char* baseB = base + 8192;
    const int swz = (lo & 7) << 4;
    short8 af[4], bf[4];
#pragma unroll
    for (int i = 0; i < 4; ++i)
      af[i] = *(const short8*)(base + (i * 16 + lo) * 128 + ((wr * 64 + hi * 16) ^ swz));
#pragma unroll
    for (int j = 0; j < 4; ++j)
      bf[j] = *(const short8*)(baseB + (j * 16 + lo) * 128 + ((wc * 64 + hi * 16) ^ swz));
    __builtin_amdgcn_s_setprio(1);
#pragma unroll
    for (int i = 0; i < 4; ++i)
#pragma unroll
      for (int j = 0; j < 4; ++j)
        acc[i][j] = mfma_bf16(af[i], bf[j], acc[i][j]);
    __builtin_amdgcn_s_setprio(0);
  };

  stage(0, 0);
  stage(1, 1);
  for (int t = 0; t < NT - 2; ++t) {
    stage((t + 2) % 3, t + 2);
    VMCNT(8);
    bar();
    compute(t % 3);
    bar();
  }
  VMCNT(4);
  bar();
  compute((NT - 2) % 3);
  bar();
  VMCNT(0);
  bar();
  compute((NT - 1) % 3);

#pragma unroll
  for (int j = 0; j < 4; ++j) {
    const int n = n0 + wc * 64 + j * 16 + lo;
    const float bv = bias[n];
#pragma unroll
    for (int i = 0; i < 4; ++i) {
      const int mrow = m0 + wr * 64 + i * 16 + hi * 4;
#pragma unroll
      for (int r = 0; r < 4; ++r)
        outF[(size_t)(mrow + r) * kC + n] = acc[i][j][r] + bv;
    }
  }
}

// ---- causal flash attention v3 (r7, validated) ----
__global__ __launch_bounds__(256) void attn_kernel(
    const u16* __restrict__ Q, const u16* __restrict__ K,
    const u16* __restrict__ VT, u16* __restrict__ Y) {
  __shared__ u16 P[4][32][72];   // per-wave P tile, 144B rows

  const int idx = blockIdx.x;
  const int qi = 4 - (idx >> 9);     // heavy-first
  const int bh = idx & 511;
  const int wave = threadIdx.x >> 6;
  const int lane = threadIdx.x & 63;
  const int lo = lane & 15;
  const int hi = lane >> 4;
  const int q0 = qi * 128 + wave * 32;
  if (q0 >= kT) return;

  const u16* Qb = Q + (size_t)bh * kT * kD;
  const u16* Kb = K + (size_t)bh * kT * kD;
  const u16* Vb = VT + (size_t)bh * kD * kT;

  short8 qf[2][2];
#pragma unroll
  for (int h = 0; h < 2; ++h) {
    const u16* qp = Qb + (q0 + h * 16 + lo) * kD + hi * 8;
    qf[h][0] = *(const short8*)qp;
    qf[h][1] = *(const short8*)(qp + 32);
  }

  f32x4 acc[2][4] = {};
  float mrun[2] = {-3e38f, -3e38f};
  float lsum[2] = {0.f, 0.f};

  short8 kf[4][2];
#pragma unroll
  for (int kc = 0; kc < 4; ++kc) {
    const u16* kp = Kb + (kc * 16 + lo) * kD + hi * 8;
    kf[kc][0] = *(const short8*)kp;
    kf[kc][1] = *(const short8*)(kp + 32);
  }

  const int kv_end = q0 + 32;
  for (int kv = 0; kv < kv_end; kv += 64) {
    f32x4 s[2][4];
#pragma unroll
    for (int kc = 0; kc < 4; ++kc)
#pragma unroll
      for (int h = 0; h < 2; ++h) {
        f32x4 z = {0.f, 0.f, 0.f, 0.f};
        z = mfma_bf16(kf[kc][0], qf[h][0], z);
        z = mfma_bf16(kf[kc][1], qf[h][1], z);
        s[h][kc] = z;
      }
    short8 vf[4][2];
#pragma unroll
    for (int nt = 0; nt < 4; ++nt) {
      const u16* vp = Vb + (nt * 16 + lo) * kT + kv + hi * 8;
      vf[nt][0] = *(const short8*)vp;
      vf[nt][1] = *(const short8*)(vp + 32);
    }
    if (kv + 64 < kv_end) {
#pragma unroll
      for (int kc = 0; kc < 4; ++kc) {
        const u16* kp = Kb + (kv + 64 + kc * 16 + lo) * kD + hi * 8;
        kf[kc][0] = *(const short8*)kp;
        kf[kc][1] = *(const short8*)(kp + 32);
      }
    }
    if (kv + 63 > q0) {
#pragma unroll
      for (int h = 0; h < 2; ++h) {
        const int q = q0 + h * 16 + lo;
#pragma unroll
        for (int kc = 0; kc < 4; ++kc)
#pragma unroll
          for (int r = 0; r < 4; ++r)
            if (kv + kc * 16 + hi * 4 + r > q) s[h][kc][r] = -3e38f;
      }
    }
#pragma unroll
    for (int h = 0; h < 2; ++h) {
      float m01 = fmaxf(fmaxf(s[h][0][0], s[h][0][1]), fmaxf(s[h][0][2], s[h][0][3]));
      float m23 = fmaxf(fmaxf(s[h][1][0], s[h][1][1]), fmaxf(s[h][1][2], s[h][1][3]));
      float m45 = fmaxf(fmaxf(s[h][2][0], s[h][2][1]), fmaxf(s[h][2][2], s[h][2][3]));
      float m67 = fmaxf(fmaxf(s[h][3][0], s[h][3][1]), fmaxf(s[h][3][2], s[h][3][3]));
      float pm = fmaxf(fmaxf(m01, m23), fmaxf(m45, m67));
      pm = fmaxf(pm, __shfl_xor(pm, 16));
      pm = fmaxf(pm, __shfl_xor(pm, 32));
      const float mnew = fmaxf(mrun[h], pm);
      const float corr = fexp2(mrun[h] - mnew);
      mrun[h] = mnew;
      float psum = 0.f;
#pragma unroll
      for (int kc = 0; kc < 4; ++kc) {
        u16x4 pk;
#pragma unroll
        for (int r = 0; r < 4; ++r) {
          const float pv = fexp2(s[h][kc][r] - mnew);
          psum += pv;
          pk[r] = to_bf16(pv);
        }
        *(u16x4*)&P[wave][h * 16 + lo][kc * 16 + hi * 4] = pk;
      }
      lsum[h] = lsum[h] * corr + psum;
#pragma unroll
      for (int nt = 0; nt < 4; ++nt)
#pragma unroll
        for (int r = 0; r < 4; ++r) acc[h][nt][r] *= corr;
    }
    short8 pf[2][2];
#pragma unroll
    for (int h = 0; h < 2; ++h) {
      pf[h][0] = *(const short8*)&P[wave][h * 16 + lo][hi * 8];
      pf[h][1] = *(const short8*)&P[wave][h * 16 + lo][32 + hi * 8];
    }
#pragma unroll
    for (int nt = 0; nt < 4; ++nt)
#pragma unroll
      for (int h = 0; h < 2; ++h) {
        acc[h][nt] = mfma_bf16(pf[h][0], vf[nt][0], acc[h][nt]);
        acc[h][nt] = mfma_bf16(pf[h][1], vf[nt][1], acc[h][nt]);
      }
  }

#pragma unroll
  for (int h = 0; h < 2; ++h) {
    lsum[h] += __shfl_xor(lsum[h], 16);
    lsum[h] += __shfl_xor(lsum[h], 32);
  }
  const int b = bh >> 4, hh = bh & 15;
#pragma unroll
  for (int h = 0; h < 2; ++h)
#pragma unroll
    for (int r = 0; r < 4; ++r) {
      const float linv = 1.0f / __shfl(lsum[h], hi * 4 + r);
      const int t = q0 + h * 16 + hi * 4 + r;
      const size_t base = ((size_t)(b * kT + t) * kH + hh) * kD;
#pragma unroll
      for (int nt = 0; nt < 4; ++nt)
        Y[base + nt * 16 + lo] = to_bf16(acc[h][nt][r] * linv);
    }
}

}  // namespace

extern "C" void kernel_launch(void* const* d_in, const int* in_sizes, int n_in,
                              void* d_out, int out_size, void* d_ws, size_t ws_size,
                              hipStream_t stream) {
  (void)in_sizes; (void)n_in; (void)out_size; (void)ws_size;
  const float* emb   = (const float*)d_in[0];
  const float* wqkv  = (const float*)d_in[1];
  const float* bqkv  = (const float*)d_in[2];
  const float* wproj = (const float*)d_in[3];
  const float* bproj = (const float*)d_in[4];
  float* out = (float*)d_out;

  char* p = (char*)d_ws;
  u16* embb   = (u16*)p; p += (size_t)kM * kC * 2;
  u16* wqkvt  = (u16*)p; p += (size_t)kNqkv * kC * 2;
  u16* wprojt = (u16*)p; p += (size_t)kC * kC * 2;
  u16* Qh     = (u16*)p; p += (size_t)kM * kC * 2;
  u16* Kh     = (u16*)p; p += (size_t)kM * kC * 2;
  u16* VTh    = (u16*)p; p += (size_t)kM * kC * 2;
  u16* Yh     = (u16*)p; p += (size_t)kM * kC * 2;

  const int n4 = kM * kC / 4;
  cvt_bf16_kernel<<<dim3((n4 + 255) / 256), 256, 0, stream>>>(emb, embb, n4);
  tconv_kernel<<<dim3(kNqkv / 32, kC / 32), dim3(32, 8), 0, stream>>>(wqkv, wqkvt, kC, kNqkv);
  tconv_kernel<<<dim3(kC / 32, kC / 32), dim3(32, 8), 0, stream>>>(wproj, wprojt, kC, kC);
  gemm_qkv<<<dim3(kNqkv / 128, kM / 256), 512, 0, stream>>>(
      embb, wqkvt, bqkv, Qh, Kh, VTh);
  attn_kernel<<<dim3(5 * kB * kH), 256, 0, stream>>>(Qh, Kh, VTh, Yh);
  gemm_proj<<<dim3(kC / 128, kM / 128), 256, 0, stream>>>(
      Yh, wprojt, bproj, out);
}